// Round 2
// baseline (476.078 us; speedup 1.0000x reference)
//
#include <hip/hip_runtime.h>
#include <hip/hip_bf16.h>
#include <math.h>

typedef __bf16 bf16;
typedef __bf16 bf16x8 __attribute__((ext_vector_type(8)));
typedef float f32x4 __attribute__((ext_vector_type(4)));

#define DEV __device__ __forceinline__

// ---------------- problem sizes ----------------
#define Bsz 2
#define Lseq 2048
#define Dm 1024
#define Hh 16
#define HD 64
#define BL (Bsz * Lseq)   // 4096 rows
#define TN (3 * Dm)       // 3072

// ---------------- workspace layout (bytes) ----------------
// total 42.5 MB (was 101.2 MB -- round-1 post-timing failure attributed to
// ws overflow corrupting neighboring allocations; tail buffers rewritten each
// call poisoned d_in for subsequent replays).
#define OFF_XATT  ((size_t)0)                            // xbf bf16 8.39MB; att aliases after gemm1
#define OFF_WQKVT (OFF_XATT  + (size_t)BL * Dm * 2)      // 6.29MB
#define OFF_WOUTT (OFF_WQKVT + (size_t)TN * Dm * 2)      // 2.10MB
#define OFF_TAB   (OFF_WOUTT + (size_t)Dm * Dm * 2)      // 0.52MB
#define OFF_Q     (OFF_TAB   + (size_t)Lseq * 32 * 8)    // 8.39MB q bf16 [32][2048][64]
#define OFF_K     (OFF_Q     + (size_t)BL * Dm * 2)      // 8.39MB
#define OFF_VT    (OFF_K     + (size_t)BL * Dm * 2)      // 8.39MB vT bf16 [32][64][2048]
// end = 42.5 MB

// ---------------- helpers ----------------
DEV float redmax16(float v) {
    v = fmaxf(v, __shfl_xor(v, 1));
    v = fmaxf(v, __shfl_xor(v, 2));
    v = fmaxf(v, __shfl_xor(v, 4));
    v = fmaxf(v, __shfl_xor(v, 8));
    return v;
}
DEV float redsum16(float v) {
    v += __shfl_xor(v, 1);
    v += __shfl_xor(v, 2);
    v += __shfl_xor(v, 4);
    v += __shfl_xor(v, 8);
    return v;
}

// ---------------- stage 0: convert x to bf16 ----------------
__global__ __launch_bounds__(256) void k_convert(const float* __restrict__ in,
                                                 bf16* __restrict__ out) {
    int i = blockIdx.x * 256 + threadIdx.x;
    const float4* in4 = (const float4*)in;
    float4 a = in4[i * 2];
    float4 b = in4[i * 2 + 1];
    bf16x8 o;
    o[0] = (bf16)a.x; o[1] = (bf16)a.y; o[2] = (bf16)a.z; o[3] = (bf16)a.w;
    o[4] = (bf16)b.x; o[5] = (bf16)b.y; o[6] = (bf16)b.z; o[7] = (bf16)b.w;
    ((bf16x8*)out)[i] = o;
}

// ---------------- stage 0b: transpose fp32 [R][C] -> bf16 [C][R] ----------------
__global__ __launch_bounds__(256) void k_transpose(const float* __restrict__ in,
                                                   bf16* __restrict__ out,
                                                   int R, int C) {
    __shared__ float t[32][33];
    int bx = blockIdx.x * 32;
    int by = blockIdx.y * 32;
    int tx = threadIdx.x, ty = threadIdx.y;
#pragma unroll
    for (int i = 0; i < 32; i += 8)
        t[ty + i][tx] = in[(size_t)(by + ty + i) * C + bx + tx];
    __syncthreads();
#pragma unroll
    for (int i = 0; i < 32; i += 8)
        out[(size_t)(bx + ty + i) * R + by + tx] = (bf16)t[tx][ty + i];
}

// ---------------- stage 0c: sin/cos table [2048][32] {sin,cos} ----------------
__global__ __launch_bounds__(256) void k_sincos(float2* __restrict__ tab) {
    int idx = blockIdx.x * 256 + threadIdx.x;
    int pos = idx >> 5, t = idx & 31;
    float theta = powf(10000.0f, -(float)t * (1.0f / 32.0f));
    float f = (float)pos * theta;
    tab[idx] = make_float2(sinf(f), cosf(f));
}

// ---------------- bf16 GEMM, 128x128 tile, BK=64, XOR-swizzled LDS ----------------
// EPI=0: C[M][N] fp32 = A*BT^T + bias
// EPI=1: fused QKV epilogue: RoPE'd q (scaled 1/8), RoPE'd k, transposed vT, all bf16
template <int EPI>
__global__ __launch_bounds__(256) void k_gemm(const bf16* __restrict__ A,
                                              const bf16* __restrict__ BT,
                                              const float* __restrict__ bias,
                                              float* __restrict__ C,
                                              bf16* __restrict__ qo,
                                              bf16* __restrict__ ko,
                                              bf16* __restrict__ vt,
                                              const float2* __restrict__ tab,
                                              int N, int K) {
    __shared__ uint4 smem4[2048];   // 32KB: A tile 16KB + B tile 16KB
    char* Al = (char*)smem4;
    char* Bl = (char*)smem4 + 16384;
    const int tid = threadIdx.x;
    const int w = tid >> 6, lane = tid & 63, lg = lane >> 4, lr = lane & 15;
    const int m0 = blockIdx.y * 128, n0 = blockIdx.x * 128;
    const int wm = (w >> 1) * 64, wn = (w & 1) * 64;
    const char* Ab = (const char*)A;
    const char* Bb = (const char*)BT;
    const size_t Kb = (size_t)K * 2;

    f32x4 acc[4][4] = {};

    const int lrow = lane >> 3;
    const int lcb = (lane & 7) * 16;

    for (int kt = 0; kt < K; kt += 64) {
#pragma unroll
        for (int c = 0; c < 4; ++c) {
            int chunk = w * 4 + c;
            int row = chunk * 8 + lrow;
            int scb = lcb ^ ((row & 7) << 4);
            uint4 va = *(const uint4*)(Ab + (size_t)(m0 + row) * Kb + kt * 2 + lcb);
            uint4 vb = *(const uint4*)(Bb + (size_t)(n0 + row) * Kb + kt * 2 + lcb);
            *(uint4*)(Al + row * 128 + scb) = va;
            *(uint4*)(Bl + row * 128 + scb) = vb;
        }
        __syncthreads();
#pragma unroll
        for (int kf = 0; kf < 2; ++kf) {
            bf16x8 af[4], bfr[4];
#pragma unroll
            for (int i = 0; i < 4; ++i) {
                int ra = wm + i * 16 + lr;
                af[i] = *(const bf16x8*)(Al + ra * 128 + ((kf * 64 + lg * 16) ^ ((ra & 7) << 4)));
                int rb = wn + i * 16 + lr;
                bfr[i] = *(const bf16x8*)(Bl + rb * 128 + ((kf * 64 + lg * 16) ^ ((rb & 7) << 4)));
            }
#pragma unroll
            for (int i = 0; i < 4; ++i)
#pragma unroll
                for (int j = 0; j < 4; ++j)
                    acc[i][j] = __builtin_amdgcn_mfma_f32_16x16x32_bf16(af[i], bfr[j], acc[i][j], 0, 0, 0);
        }
        __syncthreads();
    }

    if constexpr (EPI == 0) {
        // C layout: col=lane&15, row=(lane>>4)*4+reg
#pragma unroll
        for (int i = 0; i < 4; ++i) {
            int row = m0 + wm + i * 16 + lg * 4;
#pragma unroll
            for (int j = 0; j < 4; ++j) {
                int col = n0 + wn + j * 16 + lr;
                float bv = bias[col];
#pragma unroll
                for (int r = 0; r < 4; ++r)
                    C[(size_t)(row + r) * N + col] = acc[i][j][r] + bv;
            }
        }
    } else {
        // fused QKV epilogue. Wave tile = 64 rows x 64 cols = one head's cols.
        const int phase = n0 >> 10;            // 0=q 1=k 2=v
        const int c0 = n0 + wn;                // 64-aligned global col base
        const int h = (c0 & 1023) >> 6;
        const int b = m0 >> 11;
        const int bh = b * 16 + h;
        const int lbase = (m0 & 2047) + wm;    // seq position base of wave rows
        float bv[4];
#pragma unroll
        for (int j = 0; j < 4; ++j) bv[j] = bias[c0 + j * 16 + lr];
        float* Lw = (float*)((char*)smem4 + w * 4096);   // per-wave 16x64 fp32 tile

#pragma unroll 1
        for (int i = 0; i < 4; ++i) {
            // write this 16-row block (rows rl=lg*4+r, cols d=j*16+lr) + bias
#pragma unroll
            for (int j = 0; j < 4; ++j)
#pragma unroll
                for (int r = 0; r < 4; ++r)
                    Lw[(lg * 4 + r) * 64 + j * 16 + lr] = acc[i][j][r] + bv[j];
            __syncthreads();
            if (phase < 2) {
                const float scale = (phase == 0) ? 0.125f : 1.0f;
                bf16* dst = (phase == 0 ? qo : ko) + (size_t)bh * Lseq * 64;
#pragma unroll
                for (int j = 0; j < 4; ++j)
#pragma unroll
                    for (int r = 0; r < 4; ++r) {
                        int rl = lg * 4 + r;
                        int d = j * 16 + lr;
                        int l = lbase + i * 16 + rl;
                        float v = Lw[rl * 64 + d];
                        int dp = (d < 32) ? (2 * d + 1) : (2 * d - 64);
                        float p = Lw[rl * 64 + dp];
                        float2 f = tab[l * 32 + (d & 31)];
                        float val = ((d < 32) ? (v - p) * f.x : (v + p) * f.y) * scale;
                        dst[(size_t)l * 64 + d] = (bf16)val;
                    }
            } else {
                // V: write transposed, lane owns col d=lane, 16 consecutive l
                int d = lane;
                int lb = lbase + i * 16;
                bf16x8 o1, o2;
#pragma unroll
                for (int rw = 0; rw < 8; ++rw) {
                    o1[rw] = (bf16)Lw[rw * 64 + d];
                    o2[rw] = (bf16)Lw[(rw + 8) * 64 + d];
                }
                bf16* dst = vt + ((size_t)bh * 64 + d) * Lseq + lb;
                *(bf16x8*)dst = o1;
                *(bf16x8*)(dst + 8) = o2;
            }
            __syncthreads();
        }
    }
}

// ---------------- stage 3: flash attention ----------------
// Q,K bf16 [32][2048][64] (q pre-scaled 1/8), Vt bf16 [32][64][2048]
// out: att bf16 [4096][1024]. Block: 4 waves, Q-tile 128 rows, KV tile 64.
__global__ __launch_bounds__(256) void k_attn(const bf16* __restrict__ Q,
                                              const bf16* __restrict__ Kt,
                                              const bf16* __restrict__ Vt,
                                              bf16* __restrict__ O) {
    __shared__ uint4 smem4[2048];   // 32KB
    char* Kl = (char*)smem4;
    char* Vl = (char*)smem4 + 8192;
    char* Pl = (char*)smem4 + 16384;
    const int tid = threadIdx.x;
    const int w = tid >> 6, lane = tid & 63, lg = lane >> 4, lr = lane & 15;
    const int bid = blockIdx.x;
    const int bh = bid >> 4, qt = bid & 15;
    const int q0 = qt * 128;
    const char* qb = (const char*)(Q + (size_t)bh * Lseq * 64);
    const char* kb = (const char*)(Kt + (size_t)bh * Lseq * 64);
    const char* vb = (const char*)(Vt + (size_t)bh * 64 * Lseq);
    char* Pw = Pl + w * 4096;

    bf16x8 qf[2][2];
#pragma unroll
    for (int m = 0; m < 2; ++m)
#pragma unroll
        for (int kf = 0; kf < 2; ++kf)
            qf[m][kf] = *(const bf16x8*)(qb + (size_t)(q0 + w * 32 + m * 16 + lr) * 128 + kf * 64 + lg * 16);

    float mrow[2][4], lrow[2][4];
    f32x4 o[2][4] = {};
#pragma unroll
    for (int m = 0; m < 2; ++m)
#pragma unroll
        for (int r = 0; r < 4; ++r) { mrow[m][r] = -1e30f; lrow[m][r] = 0.f; }

    const int lrow8 = lane >> 3;
    const int lcb = (lane & 7) * 16;

    for (int jt = 0; jt < 32; ++jt) {
        int j0 = jt * 64;
#pragma unroll
        for (int c = 0; c < 2; ++c) {
            int chunk = w * 2 + c;
            int row = chunk * 8 + lrow8;
            int scb = lcb ^ ((row & 7) << 4);
            uint4 kv = *(const uint4*)(kb + (size_t)(j0 + row) * 128 + lcb);
            uint4 vv = *(const uint4*)(vb + (size_t)row * 4096 + (size_t)j0 * 2 + lcb);
            *(uint4*)(Kl + row * 128 + scb) = kv;
            *(uint4*)(Vl + row * 128 + scb) = vv;
        }
        __syncthreads();

        f32x4 s[2][4] = {};
#pragma unroll
        for (int kf = 0; kf < 2; ++kf) {
            bf16x8 kfrag[4];
#pragma unroll
            for (int n = 0; n < 4; ++n) {
                int j = n * 16 + lr;
                kfrag[n] = *(const bf16x8*)(Kl + j * 128 + ((kf * 64 + lg * 16) ^ ((j & 7) << 4)));
            }
#pragma unroll
            for (int m = 0; m < 2; ++m)
#pragma unroll
                for (int n = 0; n < 4; ++n)
                    s[m][n] = __builtin_amdgcn_mfma_f32_16x16x32_bf16(qf[m][kf], kfrag[n], s[m][n], 0, 0, 0);
        }

#pragma unroll
        for (int m = 0; m < 2; ++m) {
#pragma unroll
            for (int r = 0; r < 4; ++r) {
                float mx = fmaxf(fmaxf(s[m][0][r], s[m][1][r]), fmaxf(s[m][2][r], s[m][3][r]));
                mx = redmax16(mx);
                float mn = fmaxf(mrow[m][r], mx);
                float sc = __expf(mrow[m][r] - mn);
                float rs = 0.f;
#pragma unroll
                for (int n = 0; n < 4; ++n) {
                    float p = __expf(s[m][n][r] - mn);
                    s[m][n][r] = p;
                    rs += p;
                }
                rs = redsum16(rs);
                lrow[m][r] = lrow[m][r] * sc + rs;
                mrow[m][r] = mn;
#pragma unroll
                for (int n = 0; n < 4; ++n) o[m][n][r] *= sc;
                int rl = m * 16 + lg * 4 + r;
#pragma unroll
                for (int n = 0; n < 4; ++n) {
                    int jb = (n * 16 + lr) * 2;
                    *(bf16*)(Pw + rl * 128 + (jb ^ ((rl & 7) << 4))) = (bf16)s[m][n][r];
                }
            }
        }
        __syncthreads();

#pragma unroll
        for (int kj = 0; kj < 2; ++kj) {
            bf16x8 pf[2], vf[4];
#pragma unroll
            for (int m = 0; m < 2; ++m) {
                int rl = m * 16 + lr;
                pf[m] = *(const bf16x8*)(Pw + rl * 128 + ((kj * 64 + lg * 16) ^ ((rl & 7) << 4)));
            }
#pragma unroll
            for (int n = 0; n < 4; ++n) {
                int d = n * 16 + lr;
                vf[n] = *(const bf16x8*)(Vl + d * 128 + ((kj * 64 + lg * 16) ^ ((d & 7) << 4)));
            }
#pragma unroll
            for (int m = 0; m < 2; ++m)
#pragma unroll
                for (int n = 0; n < 4; ++n)
                    o[m][n] = __builtin_amdgcn_mfma_f32_16x16x32_bf16(pf[m], vf[n], o[m][n], 0, 0, 0);
        }
        __syncthreads();
    }

    const int b = bh >> 4, h = bh & 15;
#pragma unroll
    for (int m = 0; m < 2; ++m)
#pragma unroll
        for (int n = 0; n < 4; ++n)
#pragma unroll
            for (int r = 0; r < 4; ++r) {
                int row = q0 + w * 32 + m * 16 + lg * 4 + r;
                int col = h * 64 + n * 16 + lr;
                O[(size_t)(b * Lseq + row) * Dm + col] = (bf16)(o[m][n][r] / lrow[m][r]);
            }
}

// ---------------- launch ----------------
extern "C" void kernel_launch(void* const* d_in, const int* in_sizes, int n_in,
                              void* d_out, int out_size, void* d_ws, size_t ws_size,
                              hipStream_t stream) {
    (void)in_sizes; (void)n_in; (void)out_size; (void)ws_size;
    const float* x    = (const float*)d_in[0];
    const float* Wqkv = (const float*)d_in[1];
    const float* bqkv = (const float*)d_in[2];
    const float* Wout = (const float*)d_in[3];
    const float* bout = (const float*)d_in[4];
    float* out = (float*)d_out;
    char* ws = (char*)d_ws;

    bf16* xbf    = (bf16*)(ws + OFF_XATT);
    bf16* att    = (bf16*)(ws + OFF_XATT);   // aliases xbf (dead after gemm1)
    bf16* wqkvT  = (bf16*)(ws + OFF_WQKVT);
    bf16* woutT  = (bf16*)(ws + OFF_WOUTT);
    float2* tab  = (float2*)(ws + OFF_TAB);
    bf16* qb     = (bf16*)(ws + OFF_Q);
    bf16* kb     = (bf16*)(ws + OFF_K);
    bf16* vt     = (bf16*)(ws + OFF_VT);

    hipLaunchKernelGGL(k_convert, dim3((BL * Dm) / 8 / 256), dim3(256), 0, stream, x, xbf);
    hipLaunchKernelGGL(k_transpose, dim3(TN / 32, Dm / 32), dim3(32, 8), 0, stream, Wqkv, wqkvT, Dm, TN);
    hipLaunchKernelGGL(k_transpose, dim3(Dm / 32, Dm / 32), dim3(32, 8), 0, stream, Wout, woutT, Dm, Dm);
    hipLaunchKernelGGL(k_sincos, dim3(Lseq * 32 / 256), dim3(256), 0, stream, tab);
    hipLaunchKernelGGL((k_gemm<1>), dim3(TN / 128, BL / 128), dim3(256), 0, stream,
                       xbf, wqkvT, bqkv, (float*)nullptr, qb, kb, vt, tab, TN, Dm);
    hipLaunchKernelGGL(k_attn, dim3(32 * 16), dim3(256), 0, stream, qb, kb, vt, att);
    hipLaunchKernelGGL((k_gemm<0>), dim3(Dm / 128, BL / 128), dim3(256), 0, stream,
                       att, woutT, bout, out, (bf16*)nullptr, (bf16*)nullptr, (bf16*)nullptr,
                       (const float2*)nullptr, Dm, Dm);
}

// Round 3
// 206.723 us; speedup vs baseline: 2.3030x; 2.3030x over previous
//
#include <hip/hip_runtime.h>
#include <hip/hip_bf16.h>
#include <math.h>

typedef __bf16 bf16;
typedef __bf16 bf16x8 __attribute__((ext_vector_type(8)));
typedef float f32x4 __attribute__((ext_vector_type(4)));

#define DEV __device__ __forceinline__

// ---------------- problem sizes ----------------
#define Bsz 2
#define Lseq 2048
#define Dm 1024
#define Hh 16
#define HD 64
#define BL (Bsz * Lseq)   // 4096 rows
#define TN (3 * Dm)       // 3072

// ---------------- workspace layout (bytes) ----------------
#define OFF_XATT  ((size_t)0)                            // xbf bf16 8.39MB; att aliases after gemm1
#define OFF_WQKVT (OFF_XATT  + (size_t)BL * Dm * 2)      // 6.29MB
#define OFF_WOUTT (OFF_WQKVT + (size_t)TN * Dm * 2)      // 2.10MB
#define OFF_TAB   (OFF_WOUTT + (size_t)Dm * Dm * 2)      // 0.52MB
#define OFF_Q     (OFF_TAB   + (size_t)Lseq * 32 * 8)    // 8.39MB q bf16 [32][2048][64]
#define OFF_K     (OFF_Q     + (size_t)BL * Dm * 2)      // 8.39MB
#define OFF_VT    (OFF_K     + (size_t)BL * Dm * 2)      // 8.39MB vT bf16 [32][64][2048]
// end = 42.5 MB

// ---------------- helpers ----------------
DEV float redmax16(float v) {
    v = fmaxf(v, __shfl_xor(v, 1));
    v = fmaxf(v, __shfl_xor(v, 2));
    v = fmaxf(v, __shfl_xor(v, 4));
    v = fmaxf(v, __shfl_xor(v, 8));
    return v;
}
DEV float redsum16(float v) {
    v += __shfl_xor(v, 1);
    v += __shfl_xor(v, 2);
    v += __shfl_xor(v, 4);
    v += __shfl_xor(v, 8);
    return v;
}

// ---------------- stage 0: convert x to bf16 ----------------
__global__ __launch_bounds__(256) void k_convert(const float* __restrict__ in,
                                                 bf16* __restrict__ out) {
    int i = blockIdx.x * 256 + threadIdx.x;
    const float4* in4 = (const float4*)in;
    float4 a = in4[i * 2];
    float4 b = in4[i * 2 + 1];
    bf16x8 o;
    o[0] = (bf16)a.x; o[1] = (bf16)a.y; o[2] = (bf16)a.z; o[3] = (bf16)a.w;
    o[4] = (bf16)b.x; o[5] = (bf16)b.y; o[6] = (bf16)b.z; o[7] = (bf16)b.w;
    ((bf16x8*)out)[i] = o;
}

// ---------------- stage 0b: transpose fp32 [R][C] -> bf16 [C][R] ----------------
__global__ __launch_bounds__(256) void k_transpose(const float* __restrict__ in,
                                                   bf16* __restrict__ out,
                                                   int R, int C) {
    __shared__ float t[32][33];
    int bx = blockIdx.x * 32;
    int by = blockIdx.y * 32;
    int tx = threadIdx.x, ty = threadIdx.y;
#pragma unroll
    for (int i = 0; i < 32; i += 8)
        t[ty + i][tx] = in[(size_t)(by + ty + i) * C + bx + tx];
    __syncthreads();
#pragma unroll
    for (int i = 0; i < 32; i += 8)
        out[(size_t)(bx + ty + i) * R + by + tx] = (bf16)t[tx][ty + i];
}

// ---------------- stage 0c: sin/cos table [2048][32] {sin,cos} ----------------
__global__ __launch_bounds__(256) void k_sincos(float2* __restrict__ tab) {
    int idx = blockIdx.x * 256 + threadIdx.x;
    int pos = idx >> 5, t = idx & 31;
    float theta = powf(10000.0f, -(float)t * (1.0f / 32.0f));
    float f = (float)pos * theta;
    tab[idx] = make_float2(sinf(f), cosf(f));
}

// ---------------- bf16 GEMM, 128x128 tile, BK=64, XOR-swizzled LDS ----------------
// EPI=0: C[M][N] fp32 = A*BT^T + bias
// EPI=1: fused QKV epilogue: RoPE'd q (scaled 1/8), RoPE'd k, transposed vT, all bf16
// NOTE (round-2 post-mortem): the epilogue i-loop MUST be fully unrolled --
// runtime-indexed acc[i][..] demotes the whole accumulator to scratch
// (rule #20): VGPR 88, WRITE_SIZE 1.1GB, 325us/dispatch at 3% MfmaUtil.
template <int EPI>
DEV void gemm_body(const bf16* __restrict__ A,
                   const bf16* __restrict__ BT,
                   const float* __restrict__ bias,
                   float* __restrict__ C,
                   bf16* __restrict__ qo,
                   bf16* __restrict__ ko,
                   bf16* __restrict__ vt,
                   const float2* __restrict__ tab,
                   int N, int K) {
    __shared__ uint4 smem4[2048];   // 32KB: A tile 16KB + B tile 16KB
    char* Al = (char*)smem4;
    char* Bl = (char*)smem4 + 16384;
    const int tid = threadIdx.x;
    const int w = tid >> 6, lane = tid & 63, lg = lane >> 4, lr = lane & 15;
    const int m0 = blockIdx.y * 128, n0 = blockIdx.x * 128;
    const int wm = (w >> 1) * 64, wn = (w & 1) * 64;
    const char* Ab = (const char*)A;
    const char* Bb = (const char*)BT;
    const size_t Kb = (size_t)K * 2;

    f32x4 acc[4][4] = {};

    const int lrow = lane >> 3;
    const int lcb = (lane & 7) * 16;

    for (int kt = 0; kt < K; kt += 64) {
#pragma unroll
        for (int c = 0; c < 4; ++c) {
            int chunk = w * 4 + c;
            int row = chunk * 8 + lrow;
            int scb = lcb ^ ((row & 7) << 4);
            uint4 va = *(const uint4*)(Ab + (size_t)(m0 + row) * Kb + kt * 2 + lcb);
            uint4 vb = *(const uint4*)(Bb + (size_t)(n0 + row) * Kb + kt * 2 + lcb);
            *(uint4*)(Al + row * 128 + scb) = va;
            *(uint4*)(Bl + row * 128 + scb) = vb;
        }
        __syncthreads();
#pragma unroll
        for (int kf = 0; kf < 2; ++kf) {
            bf16x8 af[4], bfr[4];
#pragma unroll
            for (int i = 0; i < 4; ++i) {
                int ra = wm + i * 16 + lr;
                af[i] = *(const bf16x8*)(Al + ra * 128 + ((kf * 64 + lg * 16) ^ ((ra & 7) << 4)));
                int rb = wn + i * 16 + lr;
                bfr[i] = *(const bf16x8*)(Bl + rb * 128 + ((kf * 64 + lg * 16) ^ ((rb & 7) << 4)));
            }
#pragma unroll
            for (int i = 0; i < 4; ++i)
#pragma unroll
                for (int j = 0; j < 4; ++j)
                    acc[i][j] = __builtin_amdgcn_mfma_f32_16x16x32_bf16(af[i], bfr[j], acc[i][j], 0, 0, 0);
        }
        __syncthreads();
    }

    if constexpr (EPI == 0) {
        // C layout: col=lane&15, row=(lane>>4)*4+reg
#pragma unroll
        for (int i = 0; i < 4; ++i) {
            int row = m0 + wm + i * 16 + lg * 4;
#pragma unroll
            for (int j = 0; j < 4; ++j) {
                int col = n0 + wn + j * 16 + lr;
                float bv = bias[col];
#pragma unroll
                for (int r = 0; r < 4; ++r)
                    C[(size_t)(row + r) * N + col] = acc[i][j][r] + bv;
            }
        }
    } else {
        // fused QKV epilogue. Wave tile = 64 rows x 64 cols = one head's cols.
        const int phase = n0 >> 10;            // 0=q 1=k 2=v
        const int c0 = n0 + wn;                // 64-aligned global col base
        const int h = (c0 & 1023) >> 6;
        const int b = m0 >> 11;
        const int bh = b * 16 + h;
        const int lbase = (m0 & 2047) + wm;    // seq position base of wave rows
        float bv[4];
#pragma unroll
        for (int j = 0; j < 4; ++j) bv[j] = bias[c0 + j * 16 + lr];
        float* Lw = (float*)((char*)smem4 + w * 4096);   // per-wave 16x64 fp32 tile

#pragma unroll   // FULL unroll: i must be compile-time (acc stays in registers)
        for (int i = 0; i < 4; ++i) {
            // write this 16-row block (rows rl=lg*4+r, cols d=j*16+lr) + bias
#pragma unroll
            for (int j = 0; j < 4; ++j)
#pragma unroll
                for (int r = 0; r < 4; ++r)
                    Lw[(lg * 4 + r) * 64 + j * 16 + lr] = acc[i][j][r] + bv[j];
            __syncthreads();
            if (phase < 2) {
                const float scale = (phase == 0) ? 0.125f : 1.0f;
                bf16* dst = (phase == 0 ? qo : ko) + (size_t)bh * Lseq * 64;
#pragma unroll
                for (int j = 0; j < 4; ++j)
#pragma unroll
                    for (int r = 0; r < 4; ++r) {
                        int rl = lg * 4 + r;
                        int d = j * 16 + lr;
                        int l = lbase + i * 16 + rl;
                        float v = Lw[rl * 64 + d];
                        int dp = (d < 32) ? (2 * d + 1) : (2 * d - 64);
                        float p = Lw[rl * 64 + dp];
                        float2 f = tab[l * 32 + (d & 31)];
                        float val = ((d < 32) ? (v - p) * f.x : (v + p) * f.y) * scale;
                        dst[(size_t)l * 64 + d] = (bf16)val;
                    }
            } else {
                // V: write transposed, lane owns col d=lane, 16 consecutive l
                int d = lane;
                int lb = lbase + i * 16;
                bf16x8 o1, o2;
#pragma unroll
                for (int rw = 0; rw < 8; ++rw) {
                    o1[rw] = (bf16)Lw[rw * 64 + d];
                    o2[rw] = (bf16)Lw[(rw + 8) * 64 + d];
                }
                bf16* dst = vt + ((size_t)bh * 64 + d) * Lseq + lb;
                *(bf16x8*)dst = o1;
                *(bf16x8*)(dst + 8) = o2;
            }
            __syncthreads();
        }
    }
}

// distinctly-named wrappers so rocprof rows are unambiguous
__global__ __launch_bounds__(256) void k_gemm_qkv(const bf16* __restrict__ A,
                                                  const bf16* __restrict__ BT,
                                                  const float* __restrict__ bias,
                                                  bf16* __restrict__ qo,
                                                  bf16* __restrict__ ko,
                                                  bf16* __restrict__ vt,
                                                  const float2* __restrict__ tab) {
    gemm_body<1>(A, BT, bias, nullptr, qo, ko, vt, tab, TN, Dm);
}
__global__ __launch_bounds__(256) void k_gemm_out(const bf16* __restrict__ A,
                                                  const bf16* __restrict__ BT,
                                                  const float* __restrict__ bias,
                                                  float* __restrict__ C) {
    gemm_body<0>(A, BT, bias, C, nullptr, nullptr, nullptr, nullptr, Dm, Dm);
}

// ---------------- stage 3: flash attention ----------------
// Q,K bf16 [32][2048][64] (q pre-scaled 1/8), Vt bf16 [32][64][2048]
// out: att bf16 [4096][1024]. Block: 4 waves, Q-tile 128 rows, KV tile 64.
__global__ __launch_bounds__(256) void k_attn(const bf16* __restrict__ Q,
                                              const bf16* __restrict__ Kt,
                                              const bf16* __restrict__ Vt,
                                              bf16* __restrict__ O) {
    __shared__ uint4 smem4[2048];   // 32KB
    char* Kl = (char*)smem4;
    char* Vl = (char*)smem4 + 8192;
    char* Pl = (char*)smem4 + 16384;
    const int tid = threadIdx.x;
    const int w = tid >> 6, lane = tid & 63, lg = lane >> 4, lr = lane & 15;
    const int bid = blockIdx.x;
    const int bh = bid >> 4, qt = bid & 15;
    const int q0 = qt * 128;
    const char* qb = (const char*)(Q + (size_t)bh * Lseq * 64);
    const char* kb = (const char*)(Kt + (size_t)bh * Lseq * 64);
    const char* vb = (const char*)(Vt + (size_t)bh * 64 * Lseq);
    char* Pw = Pl + w * 4096;

    bf16x8 qf[2][2];
#pragma unroll
    for (int m = 0; m < 2; ++m)
#pragma unroll
        for (int kf = 0; kf < 2; ++kf)
            qf[m][kf] = *(const bf16x8*)(qb + (size_t)(q0 + w * 32 + m * 16 + lr) * 128 + kf * 64 + lg * 16);

    float mrow[2][4], lrow[2][4];
    f32x4 o[2][4] = {};
#pragma unroll
    for (int m = 0; m < 2; ++m)
#pragma unroll
        for (int r = 0; r < 4; ++r) { mrow[m][r] = -1e30f; lrow[m][r] = 0.f; }

    const int lrow8 = lane >> 3;
    const int lcb = (lane & 7) * 16;

    for (int jt = 0; jt < 32; ++jt) {
        int j0 = jt * 64;
#pragma unroll
        for (int c = 0; c < 2; ++c) {
            int chunk = w * 2 + c;
            int row = chunk * 8 + lrow8;
            int scb = lcb ^ ((row & 7) << 4);
            uint4 kv = *(const uint4*)(kb + (size_t)(j0 + row) * 128 + lcb);
            uint4 vv = *(const uint4*)(vb + (size_t)row * 4096 + (size_t)j0 * 2 + lcb);
            *(uint4*)(Kl + row * 128 + scb) = kv;
            *(uint4*)(Vl + row * 128 + scb) = vv;
        }
        __syncthreads();

        f32x4 s[2][4] = {};
#pragma unroll
        for (int kf = 0; kf < 2; ++kf) {
            bf16x8 kfrag[4];
#pragma unroll
            for (int n = 0; n < 4; ++n) {
                int j = n * 16 + lr;
                kfrag[n] = *(const bf16x8*)(Kl + j * 128 + ((kf * 64 + lg * 16) ^ ((j & 7) << 4)));
            }
#pragma unroll
            for (int m = 0; m < 2; ++m)
#pragma unroll
                for (int n = 0; n < 4; ++n)
                    s[m][n] = __builtin_amdgcn_mfma_f32_16x16x32_bf16(qf[m][kf], kfrag[n], s[m][n], 0, 0, 0);
        }

#pragma unroll
        for (int m = 0; m < 2; ++m) {
#pragma unroll
            for (int r = 0; r < 4; ++r) {
                float mx = fmaxf(fmaxf(s[m][0][r], s[m][1][r]), fmaxf(s[m][2][r], s[m][3][r]));
                mx = redmax16(mx);
                float mn = fmaxf(mrow[m][r], mx);
                float sc = __expf(mrow[m][r] - mn);
                float rs = 0.f;
#pragma unroll
                for (int n = 0; n < 4; ++n) {
                    float p = __expf(s[m][n][r] - mn);
                    s[m][n][r] = p;
                    rs += p;
                }
                rs = redsum16(rs);
                lrow[m][r] = lrow[m][r] * sc + rs;
                mrow[m][r] = mn;
#pragma unroll
                for (int n = 0; n < 4; ++n) o[m][n][r] *= sc;
                int rl = m * 16 + lg * 4 + r;
#pragma unroll
                for (int n = 0; n < 4; ++n) {
                    int jb = (n * 16 + lr) * 2;
                    *(bf16*)(Pw + rl * 128 + (jb ^ ((rl & 7) << 4))) = (bf16)s[m][n][r];
                }
            }
        }
        __syncthreads();

#pragma unroll
        for (int kj = 0; kj < 2; ++kj) {
            bf16x8 pf[2], vf[4];
#pragma unroll
            for (int m = 0; m < 2; ++m) {
                int rl = m * 16 + lr;
                pf[m] = *(const bf16x8*)(Pw + rl * 128 + ((kj * 64 + lg * 16) ^ ((rl & 7) << 4)));
            }
#pragma unroll
            for (int n = 0; n < 4; ++n) {
                int d = n * 16 + lr;
                vf[n] = *(const bf16x8*)(Vl + d * 128 + ((kj * 64 + lg * 16) ^ ((d & 7) << 4)));
            }
#pragma unroll
            for (int m = 0; m < 2; ++m)
#pragma unroll
                for (int n = 0; n < 4; ++n)
                    o[m][n] = __builtin_amdgcn_mfma_f32_16x16x32_bf16(pf[m], vf[n], o[m][n], 0, 0, 0);
        }
        __syncthreads();
    }

    const int b = bh >> 4, h = bh & 15;
#pragma unroll
    for (int m = 0; m < 2; ++m)
#pragma unroll
        for (int n = 0; n < 4; ++n)
#pragma unroll
            for (int r = 0; r < 4; ++r) {
                int row = q0 + w * 32 + m * 16 + lg * 4 + r;
                int col = h * 64 + n * 16 + lr;
                O[(size_t)(b * Lseq + row) * Dm + col] = (bf16)(o[m][n][r] / lrow[m][r]);
            }
}

// ---------------- launch ----------------
extern "C" void kernel_launch(void* const* d_in, const int* in_sizes, int n_in,
                              void* d_out, int out_size, void* d_ws, size_t ws_size,
                              hipStream_t stream) {
    (void)in_sizes; (void)n_in; (void)out_size; (void)ws_size;
    const float* x    = (const float*)d_in[0];
    const float* Wqkv = (const float*)d_in[1];
    const float* bqkv = (const float*)d_in[2];
    const float* Wout = (const float*)d_in[3];
    const float* bout = (const float*)d_in[4];
    float* out = (float*)d_out;
    char* ws = (char*)d_ws;

    bf16* xbf    = (bf16*)(ws + OFF_XATT);
    bf16* att    = (bf16*)(ws + OFF_XATT);   // aliases xbf (dead after gemm_qkv)
    bf16* wqkvT  = (bf16*)(ws + OFF_WQKVT);
    bf16* woutT  = (bf16*)(ws + OFF_WOUTT);
    float2* tab  = (float2*)(ws + OFF_TAB);
    bf16* qb     = (bf16*)(ws + OFF_Q);
    bf16* kb     = (bf16*)(ws + OFF_K);
    bf16* vt     = (bf16*)(ws + OFF_VT);

    hipLaunchKernelGGL(k_convert, dim3((BL * Dm) / 8 / 256), dim3(256), 0, stream, x, xbf);
    hipLaunchKernelGGL(k_transpose, dim3(TN / 32, Dm / 32), dim3(32, 8), 0, stream, Wqkv, wqkvT, Dm, TN);
    hipLaunchKernelGGL(k_transpose, dim3(Dm / 32, Dm / 32), dim3(32, 8), 0, stream, Wout, woutT, Dm, Dm);
    hipLaunchKernelGGL(k_sincos, dim3(Lseq * 32 / 256), dim3(256), 0, stream, tab);
    hipLaunchKernelGGL(k_gemm_qkv, dim3(TN / 128, BL / 128), dim3(256), 0, stream,
                       xbf, wqkvT, bqkv, qb, kb, vt, tab);
    hipLaunchKernelGGL(k_attn, dim3(32 * 16), dim3(256), 0, stream, qb, kb, vt, att);
    hipLaunchKernelGGL(k_gemm_out, dim3(Dm / 128, BL / 128), dim3(256), 0, stream,
                       att, woutT, bout, out);
}

// Round 4
// 149.375 us; speedup vs baseline: 3.1871x; 1.3839x over previous
//
#include <hip/hip_runtime.h>
#include <hip/hip_bf16.h>
#include <math.h>

typedef __bf16 bf16;
typedef __bf16 bf16x8 __attribute__((ext_vector_type(8)));
typedef __bf16 bf16x4 __attribute__((ext_vector_type(4)));
typedef float f32x4 __attribute__((ext_vector_type(4)));
typedef float f32x16 __attribute__((ext_vector_type(16)));

#define DEV __device__ __forceinline__

// ---------------- problem sizes ----------------
#define Bsz 2
#define Lseq 2048
#define Dm 1024
#define Hh 16
#define HD 64
#define BL (Bsz * Lseq)   // 4096 rows
#define TN (3 * Dm)       // 3072

// ---------------- workspace layout (bytes) ----------------
#define OFF_XATT  ((size_t)0)                            // xbf bf16 8.39MB; att aliases after gemm1
#define OFF_WQKVT (OFF_XATT  + (size_t)BL * Dm * 2)      // 6.29MB
#define OFF_WOUTT (OFF_WQKVT + (size_t)TN * Dm * 2)      // 2.10MB
#define OFF_TAB   (OFF_WOUTT + (size_t)Dm * Dm * 2)      // 0.52MB
#define OFF_Q     (OFF_TAB   + (size_t)Lseq * 32 * 8)    // 8.39MB q bf16 [32][2048][64]
#define OFF_K     (OFF_Q     + (size_t)BL * Dm * 2)      // 8.39MB
#define OFF_VT    (OFF_K     + (size_t)BL * Dm * 2)      // 8.39MB vT bf16 [32][64][2048]
// end = 42.5 MB

// ---------------- stage 0: convert x to bf16 ----------------
__global__ __launch_bounds__(256) void k_convert(const float* __restrict__ in,
                                                 bf16* __restrict__ out) {
    int i = blockIdx.x * 256 + threadIdx.x;
    const float4* in4 = (const float4*)in;
    float4 a = in4[i * 2];
    float4 b = in4[i * 2 + 1];
    bf16x8 o;
    o[0] = (bf16)a.x; o[1] = (bf16)a.y; o[2] = (bf16)a.z; o[3] = (bf16)a.w;
    o[4] = (bf16)b.x; o[5] = (bf16)b.y; o[6] = (bf16)b.z; o[7] = (bf16)b.w;
    ((bf16x8*)out)[i] = o;
}

// ---------------- stage 0b: transpose fp32 [R][C] -> bf16 [C][R] ----------------
__global__ __launch_bounds__(256) void k_transpose(const float* __restrict__ in,
                                                   bf16* __restrict__ out,
                                                   int R, int C) {
    __shared__ float t[32][33];
    int bx = blockIdx.x * 32;
    int by = blockIdx.y * 32;
    int tx = threadIdx.x, ty = threadIdx.y;
#pragma unroll
    for (int i = 0; i < 32; i += 8)
        t[ty + i][tx] = in[(size_t)(by + ty + i) * C + bx + tx];
    __syncthreads();
#pragma unroll
    for (int i = 0; i < 32; i += 8)
        out[(size_t)(bx + ty + i) * R + by + tx] = (bf16)t[tx][ty + i];
}

// ---------------- stage 0c: sin/cos table [2048][32] {sin,cos} ----------------
__global__ __launch_bounds__(256) void k_sincos(float2* __restrict__ tab) {
    int idx = blockIdx.x * 256 + threadIdx.x;
    int pos = idx >> 5, t = idx & 31;
    float theta = powf(10000.0f, -(float)t * (1.0f / 32.0f));
    float f = (float)pos * theta;
    tab[idx] = make_float2(sinf(f), cosf(f));
}

// ---------------- bf16 GEMM, 128x128 tile, BK=64, XOR-swizzled LDS ----------------
// NOTE: epilogue loops MUST be fully unrolled (rule #20; round-2 scratch blowup).
template <int EPI>
DEV void gemm_body(const bf16* __restrict__ A,
                   const bf16* __restrict__ BT,
                   const float* __restrict__ bias,
                   float* __restrict__ C,
                   bf16* __restrict__ qo,
                   bf16* __restrict__ ko,
                   bf16* __restrict__ vt,
                   const float2* __restrict__ tab,
                   int N, int K) {
    __shared__ uint4 smem4[2048];   // 32KB: A tile 16KB + B tile 16KB
    char* Al = (char*)smem4;
    char* Bl = (char*)smem4 + 16384;
    const int tid = threadIdx.x;
    const int w = tid >> 6, lane = tid & 63, lg = lane >> 4, lr = lane & 15;
    const int m0 = blockIdx.y * 128, n0 = blockIdx.x * 128;
    const int wm = (w >> 1) * 64, wn = (w & 1) * 64;
    const char* Ab = (const char*)A;
    const char* Bb = (const char*)BT;
    const size_t Kb = (size_t)K * 2;

    f32x4 acc[4][4] = {};

    const int lrow = lane >> 3;
    const int lcb = (lane & 7) * 16;

    for (int kt = 0; kt < K; kt += 64) {
#pragma unroll
        for (int c = 0; c < 4; ++c) {
            int chunk = w * 4 + c;
            int row = chunk * 8 + lrow;
            int scb = lcb ^ ((row & 7) << 4);
            uint4 va = *(const uint4*)(Ab + (size_t)(m0 + row) * Kb + kt * 2 + lcb);
            uint4 vb = *(const uint4*)(Bb + (size_t)(n0 + row) * Kb + kt * 2 + lcb);
            *(uint4*)(Al + row * 128 + scb) = va;
            *(uint4*)(Bl + row * 128 + scb) = vb;
        }
        __syncthreads();
#pragma unroll
        for (int kf = 0; kf < 2; ++kf) {
            bf16x8 af[4], bfr[4];
#pragma unroll
            for (int i = 0; i < 4; ++i) {
                int ra = wm + i * 16 + lr;
                af[i] = *(const bf16x8*)(Al + ra * 128 + ((kf * 64 + lg * 16) ^ ((ra & 7) << 4)));
                int rb = wn + i * 16 + lr;
                bfr[i] = *(const bf16x8*)(Bl + rb * 128 + ((kf * 64 + lg * 16) ^ ((rb & 7) << 4)));
            }
#pragma unroll
            for (int i = 0; i < 4; ++i)
#pragma unroll
                for (int j = 0; j < 4; ++j)
                    acc[i][j] = __builtin_amdgcn_mfma_f32_16x16x32_bf16(af[i], bfr[j], acc[i][j], 0, 0, 0);
        }
        __syncthreads();
    }

    if constexpr (EPI == 0) {
#pragma unroll
        for (int i = 0; i < 4; ++i) {
            int row = m0 + wm + i * 16 + lg * 4;
#pragma unroll
            for (int j = 0; j < 4; ++j) {
                int col = n0 + wn + j * 16 + lr;
                float bv = bias[col];
#pragma unroll
                for (int r = 0; r < 4; ++r)
                    C[(size_t)(row + r) * N + col] = acc[i][j][r] + bv;
            }
        }
    } else {
        const int phase = n0 >> 10;            // 0=q 1=k 2=v
        const int c0 = n0 + wn;
        const int h = (c0 & 1023) >> 6;
        const int b = m0 >> 11;
        const int bh = b * 16 + h;
        const int lbase = (m0 & 2047) + wm;
        float bv[4];
#pragma unroll
        for (int j = 0; j < 4; ++j) bv[j] = bias[c0 + j * 16 + lr];
        float* Lw = (float*)((char*)smem4 + w * 4096);

#pragma unroll   // FULL unroll: compile-time acc indices (rule #20)
        for (int i = 0; i < 4; ++i) {
#pragma unroll
            for (int j = 0; j < 4; ++j)
#pragma unroll
                for (int r = 0; r < 4; ++r)
                    Lw[(lg * 4 + r) * 64 + j * 16 + lr] = acc[i][j][r] + bv[j];
            __syncthreads();
            if (phase < 2) {
                const float scale = (phase == 0) ? 0.125f : 1.0f;
                bf16* dst = (phase == 0 ? qo : ko) + (size_t)bh * Lseq * 64;
#pragma unroll
                for (int j = 0; j < 4; ++j)
#pragma unroll
                    for (int r = 0; r < 4; ++r) {
                        int rl = lg * 4 + r;
                        int d = j * 16 + lr;
                        int l = lbase + i * 16 + rl;
                        float v = Lw[rl * 64 + d];
                        int dp = (d < 32) ? (2 * d + 1) : (2 * d - 64);
                        float p = Lw[rl * 64 + dp];
                        float2 f = tab[l * 32 + (d & 31)];
                        float val = ((d < 32) ? (v - p) * f.x : (v + p) * f.y) * scale;
                        dst[(size_t)l * 64 + d] = (bf16)val;
                    }
            } else {
                int d = lane;
                int lb = lbase + i * 16;
                bf16x8 o1, o2;
#pragma unroll
                for (int rw = 0; rw < 8; ++rw) {
                    o1[rw] = (bf16)Lw[rw * 64 + d];
                    o2[rw] = (bf16)Lw[(rw + 8) * 64 + d];
                }
                bf16* dst = vt + ((size_t)bh * 64 + d) * Lseq + lb;
                *(bf16x8*)dst = o1;
                *(bf16x8*)(dst + 8) = o2;
            }
            __syncthreads();
        }
    }
}

__global__ __launch_bounds__(256) void k_gemm_qkv(const bf16* __restrict__ A,
                                                  const bf16* __restrict__ BT,
                                                  const float* __restrict__ bias,
                                                  bf16* __restrict__ qo,
                                                  bf16* __restrict__ ko,
                                                  bf16* __restrict__ vt,
                                                  const float2* __restrict__ tab) {
    gemm_body<1>(A, BT, bias, nullptr, qo, ko, vt, tab, TN, Dm);
}
__global__ __launch_bounds__(256) void k_gemm_out(const bf16* __restrict__ A,
                                                  const bf16* __restrict__ BT,
                                                  const float* __restrict__ bias,
                                                  float* __restrict__ C) {
    gemm_body<0>(A, BT, bias, C, nullptr, nullptr, nullptr, nullptr, Dm, Dm);
}

// ---------------- stage 3: flash attention (swapped-operand, 32x32x16) ------
// S^T = mfma(K, Q): lane owns full score row for q = lane&31 (rows j = crow).
// O^T = mfma(V^T, P^T): accumulator col = q = lane&31 too -> softmax state,
// rescale and 1/l all lane-local. P stays in registers (pack + shfl_xor(32)).
// Block: 4 waves x 32 q-rows = 128 q; KV tile 64, double-buffered LDS.
DEV f32x16 mfma32(bf16x8 a, bf16x8 b, f32x16 c) {
    return __builtin_amdgcn_mfma_f32_32x32x16_bf16(a, b, c, 0, 0, 0);
}
DEV unsigned packbf(float lo, float hi) {
    unsigned short a = __builtin_bit_cast(unsigned short, (bf16)lo);
    unsigned short b = __builtin_bit_cast(unsigned short, (bf16)hi);
    return (unsigned)a | ((unsigned)b << 16);
}

__global__ __launch_bounds__(256, 2) void k_attn(const bf16* __restrict__ Q,
                                                 const bf16* __restrict__ Kt,
                                                 const bf16* __restrict__ Vt,
                                                 bf16* __restrict__ Op) {
    __shared__ uint4 smem4[2048];   // 32KB: [buf][K 8K | V 8K] x2
    char* base = (char*)smem4;
    const int tid = threadIdx.x;
    const int w = tid >> 6, lane = tid & 63;
    const int hi = lane >> 5, l31 = lane & 31;
    const int bid = blockIdx.x;
    const int bh = bid >> 4, qt = bid & 15;
    const int q0 = qt * 128 + w * 32;
    const char* qb = (const char*)(Q + (size_t)bh * Lseq * 64);
    const char* kb = (const char*)(Kt + (size_t)bh * Lseq * 64);
    const char* vb = (const char*)(Vt + (size_t)bh * 64 * Lseq);

    // Q frags (B-operand): elem i = Q[q0+l31][kst*16 + hi*8 + i]
    bf16x8 qf[4];
#pragma unroll
    for (int kst = 0; kst < 4; ++kst)
        qf[kst] = *(const bf16x8*)(qb + (size_t)(q0 + l31) * 128 + kst * 32 + hi * 16);

    f32x16 o0 = {}, o1 = {};
    float m = -1e30f, lsum = 0.f;

    const int r0 = w * 16 + (lane >> 3);       // staging rows r0, r0+8
    const int cb = (lane & 7) * 16;
    const int swz = cb ^ ((r0 & 7) << 4);      // (r0+8)&7 == r0&7

    // prologue: stage tile 0 into buf 0
    {
        uint4 sk0 = *(const uint4*)(kb + (size_t)r0 * 128 + cb);
        uint4 sk1 = *(const uint4*)(kb + (size_t)(r0 + 8) * 128 + cb);
        uint4 sv0 = *(const uint4*)(vb + (size_t)r0 * 4096 + cb);
        uint4 sv1 = *(const uint4*)(vb + (size_t)(r0 + 8) * 4096 + cb);
        *(uint4*)(base + r0 * 128 + swz) = sk0;
        *(uint4*)(base + (r0 + 8) * 128 + swz) = sk1;
        *(uint4*)(base + 8192 + r0 * 128 + swz) = sv0;
        *(uint4*)(base + 8192 + (r0 + 8) * 128 + swz) = sv1;
    }
    __syncthreads();

    for (int jt = 0; jt < 32; ++jt) {
        const int cur = jt & 1;
        const char* Kl = base + cur * 16384;
        const char* Vl = Kl + 8192;
        char* Kn = base + (cur ^ 1) * 16384;
        char* Vn = Kn + 8192;

        // issue next-tile loads early (T14-lite)
        uint4 sk0, sk1, sv0, sv1;
        if (jt < 31) {
            const int j0n = (jt + 1) * 64;
            sk0 = *(const uint4*)(kb + (size_t)(j0n + r0) * 128 + cb);
            sk1 = *(const uint4*)(kb + (size_t)(j0n + r0 + 8) * 128 + cb);
            sv0 = *(const uint4*)(vb + (size_t)r0 * 4096 + j0n * 2 + cb);
            sv1 = *(const uint4*)(vb + (size_t)(r0 + 8) * 4096 + j0n * 2 + cb);
        }

        // S^T = K * Q^T : s0 = j rows 0..31, s1 = 32..63 (col q = l31)
        f32x16 s0 = {}, s1 = {};
#pragma unroll
        for (int kst = 0; kst < 4; ++kst) {
            const int byt = kst * 32 + hi * 16;
            const int ra = l31, rb2 = 32 + l31;
            bf16x8 ka = *(const bf16x8*)(Kl + ra * 128 + (byt ^ ((ra & 7) << 4)));
            bf16x8 kc = *(const bf16x8*)(Kl + rb2 * 128 + (byt ^ ((rb2 & 7) << 4)));
            s0 = mfma32(ka, qf[kst], s0);
            s1 = mfma32(kc, qf[kst], s1);
        }

        // lane-local online softmax for row q = l31
        float pm = s0[0];
#pragma unroll
        for (int r = 1; r < 16; ++r) pm = fmaxf(pm, s0[r]);
#pragma unroll
        for (int r = 0; r < 16; ++r) pm = fmaxf(pm, s1[r]);
        pm = fmaxf(pm, __shfl_xor(pm, 32));
        if (!__all(pm <= m + 8.0f)) {          // defer-max (T13)
            float mn = fmaxf(m, pm);
            float sc = __expf(m - mn);
#pragma unroll
            for (int r = 0; r < 16; ++r) { o0[r] *= sc; o1[r] *= sc; }
            lsum *= sc; m = mn;
        }
        float rs = 0.f;
#pragma unroll
        for (int r = 0; r < 16; ++r) { s0[r] = __expf(s0[r] - m); rs += s0[r]; }
#pragma unroll
        for (int r = 0; r < 16; ++r) { s1[r] = __expf(s1[r] - m); rs += s1[r]; }
        rs += __shfl_xor(rs, 32);
        lsum += rs;

        // write staged tile (loads have had QK^T+softmax to land)
        if (jt < 31) {
            *(uint4*)(Kn + r0 * 128 + swz) = sk0;
            *(uint4*)(Kn + (r0 + 8) * 128 + swz) = sk1;
            *(uint4*)(Vn + r0 * 128 + swz) = sv0;
            *(uint4*)(Vn + (r0 + 8) * 128 + swz) = sv1;
        }

        // pack P to bf16 pairs, exchange halves, build B-frags (P^T)
        unsigned u[16], su[16];
#pragma unroll
        for (int t = 0; t < 8; ++t) {
            u[t]     = packbf(s0[2 * t], s0[2 * t + 1]);
            u[8 + t] = packbf(s1[2 * t], s1[2 * t + 1]);
        }
#pragma unroll
        for (int t = 0; t < 16; ++t) su[t] = __shfl_xor(u[t], 32);
        bf16x8 pf[2][2];
#pragma unroll
        for (int J = 0; J < 2; ++J)
#pragma unroll
            for (int st = 0; st < 2; ++st) {
                const int t0 = J * 8 + st * 4;
                union { unsigned wd[4]; bf16x8 v; } f;
                f.wd[0] = hi ? su[t0 + 2] : u[t0 + 0];
                f.wd[1] = hi ? su[t0 + 3] : u[t0 + 1];
                f.wd[2] = hi ? u[t0 + 2] : su[t0 + 0];
                f.wd[3] = hi ? u[t0 + 3] : su[t0 + 1];
                pf[J][st] = f.v;
            }

        // O^T += V^T * P^T : o0 = d rows 0..31, o1 = 32..63 (col q = l31)
#pragma unroll
        for (int J = 0; J < 2; ++J)
#pragma unroll
            for (int st = 0; st < 2; ++st) {
                const int byt = J * 64 + st * 32 + hi * 16;
                const int rv0 = l31, rv1 = 32 + l31;
                bf16x8 v0 = *(const bf16x8*)(Vl + rv0 * 128 + (byt ^ ((rv0 & 7) << 4)));
                bf16x8 v1 = *(const bf16x8*)(Vl + rv1 * 128 + (byt ^ ((rv1 & 7) << 4)));
                o0 = mfma32(v0, pf[J][st], o0);
                o1 = mfma32(v1, pf[J][st], o1);
            }
        __syncthreads();
    }

    // epilogue: lane owns col q = l31; rows d = (r&3)+8*(r>>2)+4*hi (+32 for o1)
    const float inv = 1.0f / lsum;
    const int b = bh >> 4, h = bh & 15;
    bf16* dst = Op + (size_t)(b * Lseq + q0 + l31) * Dm + h * 64;
#pragma unroll
    for (int t = 0; t < 4; ++t) {
        bf16x4 p0, p1;
#pragma unroll
        for (int i = 0; i < 4; ++i) {
            p0[i] = (bf16)(o0[4 * t + i] * inv);
            p1[i] = (bf16)(o1[4 * t + i] * inv);
        }
        *(bf16x4*)(dst + 8 * t + 4 * hi) = p0;
        *(bf16x4*)(dst + 32 + 8 * t + 4 * hi) = p1;
    }
}

// ---------------- launch ----------------
extern "C" void kernel_launch(void* const* d_in, const int* in_sizes, int n_in,
                              void* d_out, int out_size, void* d_ws, size_t ws_size,
                              hipStream_t stream) {
    (void)in_sizes; (void)n_in; (void)out_size; (void)ws_size;
    const float* x    = (const float*)d_in[0];
    const float* Wqkv = (const float*)d_in[1];
    const float* bqkv = (const float*)d_in[2];
    const float* Wout = (const float*)d_in[3];
    const float* bout = (const float*)d_in[4];
    float* out = (float*)d_out;
    char* ws = (char*)d_ws;

    bf16* xbf    = (bf16*)(ws + OFF_XATT);
    bf16* att    = (bf16*)(ws + OFF_XATT);   // aliases xbf (dead after gemm_qkv)
    bf16* wqkvT  = (bf16*)(ws + OFF_WQKVT);
    bf16* woutT  = (bf16*)(ws + OFF_WOUTT);
    float2* tab  = (float2*)(ws + OFF_TAB);
    bf16* qb     = (bf16*)(ws + OFF_Q);
    bf16* kb     = (bf16*)(ws + OFF_K);
    bf16* vt     = (bf16*)(ws + OFF_VT);

    hipLaunchKernelGGL(k_convert, dim3((BL * Dm) / 8 / 256), dim3(256), 0, stream, x, xbf);
    hipLaunchKernelGGL(k_transpose, dim3(TN / 32, Dm / 32), dim3(32, 8), 0, stream, Wqkv, wqkvT, Dm, TN);
    hipLaunchKernelGGL(k_transpose, dim3(Dm / 32, Dm / 32), dim3(32, 8), 0, stream, Wout, woutT, Dm, Dm);
    hipLaunchKernelGGL(k_sincos, dim3(Lseq * 32 / 256), dim3(256), 0, stream, tab);
    hipLaunchKernelGGL(k_gemm_qkv, dim3(TN / 128, BL / 128), dim3(256), 0, stream,
                       xbf, wqkvT, bqkv, qb, kb, vt, tab);
    hipLaunchKernelGGL(k_attn, dim3(32 * 16), dim3(256), 0, stream, qb, kb, vt, att);
    hipLaunchKernelGGL(k_gemm_out, dim3(Dm / 128, BL / 128), dim3(256), 0, stream,
                       att, woutT, bout, out);
}

// Round 5
// 144.062 us; speedup vs baseline: 3.3047x; 1.0369x over previous
//
#include <hip/hip_runtime.h>
#include <hip/hip_bf16.h>
#include <math.h>

typedef __bf16 bf16;
typedef __bf16 bf16x8 __attribute__((ext_vector_type(8)));
typedef __bf16 bf16x4 __attribute__((ext_vector_type(4)));
typedef float f32x4 __attribute__((ext_vector_type(4)));
typedef float f32x16 __attribute__((ext_vector_type(16)));

#define DEV __device__ __forceinline__
#define AS1(p) ((const __attribute__((address_space(1))) void*)(p))
#define AS3(p) ((__attribute__((address_space(3))) void*)(p))

// ---------------- problem sizes ----------------
#define Bsz 2
#define Lseq 2048
#define Dm 1024
#define Hh 16
#define HD 64
#define BL (Bsz * Lseq)   // 4096 rows
#define TN (3 * Dm)       // 3072

#define LOG2E 1.44269504088896f

// ---------------- workspace layout (bytes) ----------------
#define OFF_XATT  ((size_t)0)                            // xbf bf16 8.39MB; att aliases after gemm1
#define OFF_WQKVT (OFF_XATT  + (size_t)BL * Dm * 2)      // 6.29MB
#define OFF_WOUTT (OFF_WQKVT + (size_t)TN * Dm * 2)      // 2.10MB
#define OFF_TAB   (OFF_WOUTT + (size_t)Dm * Dm * 2)      // 0.52MB
#define OFF_Q     (OFF_TAB   + (size_t)Lseq * 32 * 8)    // 8.39MB q bf16 [32][2048][64]
#define OFF_K     (OFF_Q     + (size_t)BL * Dm * 2)      // 8.39MB
#define OFF_VT    (OFF_K     + (size_t)BL * Dm * 2)      // 8.39MB vT bf16 [32][64][2048]
// end = 42.5 MB

DEV float exp2_fast(float x) {   // 2^x, single v_exp_f32 (no builtin-name risk)
    float r;
    asm("v_exp_f32 %0, %1" : "=v"(r) : "v"(x));
    return r;
}

// ---------------- stage 0: convert x to bf16 ----------------
__global__ __launch_bounds__(256) void k_convert(const float* __restrict__ in,
                                                 bf16* __restrict__ out) {
    int i = blockIdx.x * 256 + threadIdx.x;
    const float4* in4 = (const float4*)in;
    float4 a = in4[i * 2];
    float4 b = in4[i * 2 + 1];
    bf16x8 o;
    o[0] = (bf16)a.x; o[1] = (bf16)a.y; o[2] = (bf16)a.z; o[3] = (bf16)a.w;
    o[4] = (bf16)b.x; o[5] = (bf16)b.y; o[6] = (bf16)b.z; o[7] = (bf16)b.w;
    ((bf16x8*)out)[i] = o;
}

// ---------------- stage 0b: transpose fp32 [R][C] -> bf16 [C][R] ----------------
__global__ __launch_bounds__(256) void k_transpose(const float* __restrict__ in,
                                                   bf16* __restrict__ out,
                                                   int R, int C) {
    __shared__ float t[32][33];
    int bx = blockIdx.x * 32;
    int by = blockIdx.y * 32;
    int tx = threadIdx.x, ty = threadIdx.y;
#pragma unroll
    for (int i = 0; i < 32; i += 8)
        t[ty + i][tx] = in[(size_t)(by + ty + i) * C + bx + tx];
    __syncthreads();
#pragma unroll
    for (int i = 0; i < 32; i += 8)
        out[(size_t)(bx + ty + i) * R + by + tx] = (bf16)t[tx][ty + i];
}

// ---------------- stage 0c: sin/cos table [2048][32] {sin,cos} ----------------
__global__ __launch_bounds__(256) void k_sincos(float2* __restrict__ tab) {
    int idx = blockIdx.x * 256 + threadIdx.x;
    int pos = idx >> 5, t = idx & 31;
    float theta = powf(10000.0f, -(float)t * (1.0f / 32.0f));
    float f = (float)pos * theta;
    tab[idx] = make_float2(sinf(f), cosf(f));
}

// ---------------- bf16 GEMM, 128x128 tile, BK=64 ----------------
// Staging via global_load_lds (async, no VGPR round-trip): LDS dest is LINEAR
// [row][slot*16]; the XOR swizzle lives in the pre-swizzled global SOURCE
// (slot s of row r holds global chunk s ^ (r&7)) -- rule #21 both-sides pattern.
// ds_reads apply the same XOR. Epilogue loops fully unrolled (rule #20).
template <int EPI>
DEV void gemm_body(const bf16* __restrict__ A,
                   const bf16* __restrict__ BT,
                   const float* __restrict__ bias,
                   float* __restrict__ C,
                   bf16* __restrict__ qo,
                   bf16* __restrict__ ko,
                   bf16* __restrict__ vt,
                   const float2* __restrict__ tab,
                   int N, int K) {
    __shared__ uint4 smem4[2048];   // 32KB: A tile 16KB + B tile 16KB
    char* Al = (char*)smem4;
    char* Bl = (char*)smem4 + 16384;
    const int tid = threadIdx.x;
    const int w = tid >> 6, lane = tid & 63, lg = lane >> 4, lr = lane & 15;
    const int m0 = blockIdx.y * 128, n0 = blockIdx.x * 128;
    const int wm = (w >> 1) * 64, wn = (w & 1) * 64;
    const char* Ab = (const char*)A;
    const char* Bb = (const char*)BT;
    const size_t Kb = (size_t)K * 2;

    f32x4 acc[4][4] = {};

    const int rowL = lane >> 3;                    // 0..7 within 8-row group
    const int j16 = ((lane & 7) ^ rowL) * 16;      // pre-swizzled source chunk byte

    for (int kt = 0; kt < K; kt += 64) {
#pragma unroll
        for (int c = 0; c < 4; ++c) {
            const int R0 = (w * 4 + c) * 8;
            const int row = R0 + rowL;
            __builtin_amdgcn_global_load_lds(AS1(Ab + (size_t)(m0 + row) * Kb + kt * 2 + j16),
                                             AS3(Al + R0 * 128), 16, 0, 0);
            __builtin_amdgcn_global_load_lds(AS1(Bb + (size_t)(n0 + row) * Kb + kt * 2 + j16),
                                             AS3(Bl + R0 * 128), 16, 0, 0);
        }
        __syncthreads();
#pragma unroll
        for (int kf = 0; kf < 2; ++kf) {
            bf16x8 af[4], bfr[4];
#pragma unroll
            for (int i = 0; i < 4; ++i) {
                int ra = wm + i * 16 + lr;
                af[i] = *(const bf16x8*)(Al + ra * 128 + ((kf * 64 + lg * 16) ^ ((ra & 7) << 4)));
                int rb = wn + i * 16 + lr;
                bfr[i] = *(const bf16x8*)(Bl + rb * 128 + ((kf * 64 + lg * 16) ^ ((rb & 7) << 4)));
            }
#pragma unroll
            for (int i = 0; i < 4; ++i)
#pragma unroll
                for (int j = 0; j < 4; ++j)
                    acc[i][j] = __builtin_amdgcn_mfma_f32_16x16x32_bf16(af[i], bfr[j], acc[i][j], 0, 0, 0);
        }
        __syncthreads();
    }

    if constexpr (EPI == 0) {
#pragma unroll
        for (int i = 0; i < 4; ++i) {
            int row = m0 + wm + i * 16 + lg * 4;
#pragma unroll
            for (int j = 0; j < 4; ++j) {
                int col = n0 + wn + j * 16 + lr;
                float bv = bias[col];
#pragma unroll
                for (int r = 0; r < 4; ++r)
                    C[(size_t)(row + r) * N + col] = acc[i][j][r] + bv;
            }
        }
    } else {
        const int phase = n0 >> 10;            // 0=q 1=k 2=v
        const int c0 = n0 + wn;
        const int h = (c0 & 1023) >> 6;
        const int b = m0 >> 11;
        const int bh = b * 16 + h;
        const int lbase = (m0 & 2047) + wm;
        float bv[4];
#pragma unroll
        for (int j = 0; j < 4; ++j) bv[j] = bias[c0 + j * 16 + lr];
        float* Lw = (float*)((char*)smem4 + w * 4096);

#pragma unroll   // FULL unroll: compile-time acc indices (rule #20)
        for (int i = 0; i < 4; ++i) {
#pragma unroll
            for (int j = 0; j < 4; ++j)
#pragma unroll
                for (int r = 0; r < 4; ++r)
                    Lw[(lg * 4 + r) * 64 + j * 16 + lr] = acc[i][j][r] + bv[j];
            __syncthreads();
            if (phase < 2) {
                // q gets 1/8 (scores) * log2e (exp2-domain softmax) folded in
                const float scale = (phase == 0) ? 0.125f * LOG2E : 1.0f;
                bf16* dst = (phase == 0 ? qo : ko) + (size_t)bh * Lseq * 64;
#pragma unroll
                for (int j = 0; j < 4; ++j)
#pragma unroll
                    for (int r = 0; r < 4; ++r) {
                        int rl = lg * 4 + r;
                        int d = j * 16 + lr;
                        int l = lbase + i * 16 + rl;
                        float v = Lw[rl * 64 + d];
                        int dp = (d < 32) ? (2 * d + 1) : (2 * d - 64);
                        float p = Lw[rl * 64 + dp];
                        float2 f = tab[l * 32 + (d & 31)];
                        float val = ((d < 32) ? (v - p) * f.x : (v + p) * f.y) * scale;
                        dst[(size_t)l * 64 + d] = (bf16)val;
                    }
            } else {
                int d = lane;
                int lb = lbase + i * 16;
                bf16x8 o1, o2;
#pragma unroll
                for (int rw = 0; rw < 8; ++rw) {
                    o1[rw] = (bf16)Lw[rw * 64 + d];
                    o2[rw] = (bf16)Lw[(rw + 8) * 64 + d];
                }
                bf16* dst = vt + ((size_t)bh * 64 + d) * Lseq + lb;
                *(bf16x8*)dst = o1;
                *(bf16x8*)(dst + 8) = o2;
            }
            __syncthreads();
        }
    }
}

__global__ __launch_bounds__(256) void k_gemm_qkv(const bf16* __restrict__ A,
                                                  const bf16* __restrict__ BT,
                                                  const float* __restrict__ bias,
                                                  bf16* __restrict__ qo,
                                                  bf16* __restrict__ ko,
                                                  bf16* __restrict__ vt,
                                                  const float2* __restrict__ tab) {
    gemm_body<1>(A, BT, bias, nullptr, qo, ko, vt, tab, TN, Dm);
}
__global__ __launch_bounds__(256) void k_gemm_out(const bf16* __restrict__ A,
                                                  const bf16* __restrict__ BT,
                                                  const float* __restrict__ bias,
                                                  float* __restrict__ C) {
    gemm_body<0>(A, BT, bias, C, nullptr, nullptr, nullptr, nullptr, Dm, Dm);
}

// ---------------- stage 3: flash attention (swapped-operand, 32x32x16) ------
// S^T = mfma(K, Q); O^T = mfma(V^T, P^T): softmax state fully lane-local.
// LDS: fragment-major [chunk j][row] per 8KB tile: addr = j*1024 + (r^j)*16.
//   - reads (fixed j, rows p*32+l31) are contiguous 512B spans: conflict-free
//   - staging = one global_load_lds dwordx4 per chunk (linear dest, source
//     row pre-swizzled r = lane^j) -- async, drains at the tile barrier.
// Q pre-scaled by 0.125*log2e at QKV epilogue -> softmax in exp2 domain.
DEV f32x16 mfma32(bf16x8 a, bf16x8 b, f32x16 c) {
    return __builtin_amdgcn_mfma_f32_32x32x16_bf16(a, b, c, 0, 0, 0);
}
DEV unsigned packbf(float lo, float hi) {
    unsigned short a = __builtin_bit_cast(unsigned short, (bf16)lo);
    unsigned short b = __builtin_bit_cast(unsigned short, (bf16)hi);
    return (unsigned)a | ((unsigned)b << 16);
}

DEV void stage_tile(const char* kb, const char* vb, char* Kn, char* Vn,
                    int j0, int w, int lane) {
#pragma unroll
    for (int c = 0; c < 2; ++c) {
        const int j = w * 2 + c;               // chunk 0..7 (wave-uniform)
        const int rsw = lane ^ j;              // pre-swizzled source row
        __builtin_amdgcn_global_load_lds(AS1(kb + (size_t)(j0 + rsw) * 128 + j * 16),
                                         AS3(Kn + j * 1024), 16, 0, 0);
        __builtin_amdgcn_global_load_lds(AS1(vb + (size_t)rsw * 4096 + (size_t)j0 * 2 + j * 16),
                                         AS3(Vn + j * 1024), 16, 0, 0);
    }
}

__global__ __launch_bounds__(256, 2) void k_attn(const bf16* __restrict__ Q,
                                                 const bf16* __restrict__ Kt,
                                                 const bf16* __restrict__ Vt,
                                                 bf16* __restrict__ Op) {
    __shared__ uint4 smem4[2048];   // 32KB: [buf][K 8K | V 8K] x2
    char* base = (char*)smem4;
    const int tid = threadIdx.x;
    const int w = tid >> 6, lane = tid & 63;
    const int hi = lane >> 5, l31 = lane & 31;
    const int bid = blockIdx.x;
    const int bh = bid >> 4, qt = bid & 15;
    const int q0 = qt * 128 + w * 32;
    const char* qb = (const char*)(Q + (size_t)bh * Lseq * 64);
    const char* kb = (const char*)(Kt + (size_t)bh * Lseq * 64);
    const char* vb = (const char*)(Vt + (size_t)bh * 64 * Lseq);

    // Q frags (B-operand): elem i = Q[q0+l31][kst*16 + hi*8 + i]
    bf16x8 qf[4];
#pragma unroll
    for (int kst = 0; kst < 4; ++kst)
        qf[kst] = *(const bf16x8*)(qb + (size_t)(q0 + l31) * 128 + kst * 32 + hi * 16);

    f32x16 o0 = {}, o1 = {};
    float m = -1e30f, lsum = 0.f;

    // prologue: stage tile 0 into buf 0
    stage_tile(kb, vb, base, base + 8192, 0, w, lane);
    __syncthreads();

    for (int jt = 0; jt < 32; ++jt) {
        const int cur = jt & 1;
        const char* Kl = base + cur * 16384;
        const char* Vl = Kl + 8192;
        char* Kn = base + (cur ^ 1) * 16384;
        char* Vn = Kn + 8192;

        // async-stage next tile (drains at this iteration's end barrier)
        if (jt < 31) stage_tile(kb, vb, Kn, Vn, (jt + 1) * 64, w, lane);

        // S^T = K * Q^T : s0 = j rows 0..31, s1 = 32..63 (col q = l31)
        f32x16 s0 = {}, s1 = {};
        __builtin_amdgcn_s_setprio(1);
#pragma unroll
        for (int kst = 0; kst < 4; ++kst) {
            const int jK = kst * 2 + hi;
            const int x = l31 ^ jK;            // jK<8: flips low 3 bits only
            bf16x8 ka = *(const bf16x8*)(Kl + jK * 1024 + x * 16);
            bf16x8 kc = *(const bf16x8*)(Kl + jK * 1024 + (32 + x) * 16);
            s0 = mfma32(ka, qf[kst], s0);
            s1 = mfma32(kc, qf[kst], s1);
        }
        __builtin_amdgcn_s_setprio(0);

        // lane-local online softmax (exp2 domain) for row q = l31
        float pm = fmaxf(s0[0], s0[1]);
#pragma unroll
        for (int r = 2; r < 16; ++r) pm = fmaxf(pm, s0[r]);
#pragma unroll
        for (int r = 0; r < 16; ++r) pm = fmaxf(pm, s1[r]);
        pm = fmaxf(pm, __shfl_xor(pm, 32));
        if (!__all(pm <= m + 8.0f)) {          // defer-max (T13), log2 units
            float mn = fmaxf(m, pm);
            float sc = exp2_fast(m - mn);
#pragma unroll
            for (int r = 0; r < 16; ++r) { o0[r] *= sc; o1[r] *= sc; }
            lsum *= sc; m = mn;
        }
        float rs = 0.f;
#pragma unroll
        for (int r = 0; r < 16; ++r) { s0[r] = exp2_fast(s0[r] - m); rs += s0[r]; }
#pragma unroll
        for (int r = 0; r < 16; ++r) { s1[r] = exp2_fast(s1[r] - m); rs += s1[r]; }
        rs += __shfl_xor(rs, 32);
        lsum += rs;

        // pack P to bf16 pairs; exchange only the 8 words the partner consumes
        unsigned u[16];
#pragma unroll
        for (int t = 0; t < 8; ++t) {
            u[t]     = packbf(s0[2 * t], s0[2 * t + 1]);
            u[8 + t] = packbf(s1[2 * t], s1[2 * t + 1]);
        }
        unsigned snd[8], rcv[8];
#pragma unroll
        for (int J = 0; J < 2; ++J)
#pragma unroll
            for (int st = 0; st < 2; ++st) {
                const int t0 = J * 8 + st * 4, q = (J * 2 + st) * 2;
                snd[q + 0] = hi ? u[t0 + 0] : u[t0 + 2];
                snd[q + 1] = hi ? u[t0 + 1] : u[t0 + 3];
            }
#pragma unroll
        for (int t = 0; t < 8; ++t) rcv[t] = __shfl_xor(snd[t], 32);
        bf16x8 pf[2][2];
#pragma unroll
        for (int J = 0; J < 2; ++J)
#pragma unroll
            for (int st = 0; st < 2; ++st) {
                const int t0 = J * 8 + st * 4, q = (J * 2 + st) * 2;
                union { unsigned wd[4]; bf16x8 v; } f;
                f.wd[0] = hi ? rcv[q + 0] : u[t0 + 0];
                f.wd[1] = hi ? rcv[q + 1] : u[t0 + 1];
                f.wd[2] = hi ? u[t0 + 2] : rcv[q + 0];
                f.wd[3] = hi ? u[t0 + 3] : rcv[q + 1];
                pf[J][st] = f.v;
            }

        // O^T += V^T * P^T : o0 = d rows 0..31, o1 = 32..63 (col q = l31)
        __builtin_amdgcn_s_setprio(1);
#pragma unroll
        for (int J = 0; J < 2; ++J)
#pragma unroll
            for (int st = 0; st < 2; ++st) {
                const int jV = J * 4 + st * 2 + hi;
                const int x = l31 ^ jV;
                bf16x8 v0 = *(const bf16x8*)(Vl + jV * 1024 + x * 16);
                bf16x8 v1 = *(const bf16x8*)(Vl + jV * 1024 + (32 + x) * 16);
                o0 = mfma32(v0, pf[J][st], o0);
                o1 = mfma32(v1, pf[J][st], o1);
            }
        __builtin_amdgcn_s_setprio(0);
        __syncthreads();
    }

    // epilogue: lane owns col q = l31; rows d = (r&3)+8*(r>>2)+4*hi (+32 for o1)
    const float inv = 1.0f / lsum;
    const int b = bh >> 4, h = bh & 15;
    bf16* dst = Op + (size_t)(b * Lseq + q0 + l31) * Dm + h * 64;
#pragma unroll
    for (int t = 0; t < 4; ++t) {
        bf16x4 p0, p1;
#pragma unroll
        for (int i = 0; i < 4; ++i) {
            p0[i] = (bf16)(o0[4 * t + i] * inv);
            p1[i] = (bf16)(o1[4 * t + i] * inv);
        }
        *(bf16x4*)(dst + 8 * t + 4 * hi) = p0;
        *(bf16x4*)(dst + 32 + 8 * t + 4 * hi) = p1;
    }
}

// ---------------- launch ----------------
extern "C" void kernel_launch(void* const* d_in, const int* in_sizes, int n_in,
                              void* d_out, int out_size, void* d_ws, size_t ws_size,
                              hipStream_t stream) {
    (void)in_sizes; (void)n_in; (void)out_size; (void)ws_size;
    const float* x    = (const float*)d_in[0];
    const float* Wqkv = (const float*)d_in[1];
    const float* bqkv = (const float*)d_in[2];
    const float* Wout = (const float*)d_in[3];
    const float* bout = (const float*)d_in[4];
    float* out = (float*)d_out;
    char* ws = (char*)d_ws;

    bf16* xbf    = (bf16*)(ws + OFF_XATT);
    bf16* att    = (bf16*)(ws + OFF_XATT);   // aliases xbf (dead after gemm_qkv)
    bf16* wqkvT  = (bf16*)(ws + OFF_WQKVT);
    bf16* woutT  = (bf16*)(ws + OFF_WOUTT);
    float2* tab  = (float2*)(ws + OFF_TAB);
    bf16* qb     = (bf16*)(ws + OFF_Q);
    bf16* kb     = (bf16*)(ws + OFF_K);
    bf16* vt     = (bf16*)(ws + OFF_VT);

    hipLaunchKernelGGL(k_convert, dim3((BL * Dm) / 8 / 256), dim3(256), 0, stream, x, xbf);
    hipLaunchKernelGGL(k_transpose, dim3(TN / 32, Dm / 32), dim3(32, 8), 0, stream, Wqkv, wqkvT, Dm, TN);
    hipLaunchKernelGGL(k_transpose, dim3(Dm / 32, Dm / 32), dim3(32, 8), 0, stream, Wout, woutT, Dm, Dm);
    hipLaunchKernelGGL(k_sincos, dim3(Lseq * 32 / 256), dim3(256), 0, stream, tab);
    hipLaunchKernelGGL(k_gemm_qkv, dim3(TN / 128, BL / 128), dim3(256), 0, stream,
                       xbf, wqkvT, bqkv, qb, kb, vt, tab);
    hipLaunchKernelGGL(k_attn, dim3(32 * 16), dim3(256), 0, stream, qb, kb, vt, att);
    hipLaunchKernelGGL(k_gemm_out, dim3(Dm / 128, BL / 128), dim3(256), 0, stream,
                       att, woutT, bout, out);
}

// Round 6
// 141.908 us; speedup vs baseline: 3.3548x; 1.0152x over previous
//
#include <hip/hip_runtime.h>
#include <hip/hip_bf16.h>
#include <math.h>

typedef __bf16 bf16;
typedef __bf16 bf16x8 __attribute__((ext_vector_type(8)));
typedef __bf16 bf16x4 __attribute__((ext_vector_type(4)));
typedef float f32x4 __attribute__((ext_vector_type(4)));
typedef float f32x16 __attribute__((ext_vector_type(16)));

#define DEV __device__ __forceinline__
#define AS1(p) ((const __attribute__((address_space(1))) void*)(p))
#define AS3(p) ((__attribute__((address_space(3))) void*)(p))

// ---------------- problem sizes ----------------
#define Bsz 2
#define Lseq 2048
#define Dm 1024
#define Hh 16
#define HD 64
#define BL (Bsz * Lseq)   // 4096 rows
#define TN (3 * Dm)       // 3072

#define LOG2E 1.44269504088896f

// ---------------- workspace layout (bytes) ----------------
#define OFF_XATT  ((size_t)0)                            // xbf bf16 8.39MB; att aliases after gemm1
#define OFF_WQKVT (OFF_XATT  + (size_t)BL * Dm * 2)      // 6.29MB
#define OFF_WOUTT (OFF_WQKVT + (size_t)TN * Dm * 2)      // 2.10MB
#define OFF_TAB   (OFF_WOUTT + (size_t)Dm * Dm * 2)      // 0.52MB
#define OFF_Q     (OFF_TAB   + (size_t)Lseq * 32 * 8)    // 8.39MB q bf16 [32][2048][64]
#define OFF_K     (OFF_Q     + (size_t)BL * Dm * 2)      // 8.39MB
#define OFF_VT    (OFF_K     + (size_t)BL * Dm * 2)      // 8.39MB vT bf16 [32][64][2048]
// end = 42.5 MB

DEV float exp2_fast(float x) {   // 2^x, single v_exp_f32
    float r;
    asm("v_exp_f32 %0, %1" : "=v"(r) : "v"(x));
    return r;
}

// ---------------- stage 0: convert x to bf16 ----------------
__global__ __launch_bounds__(256) void k_convert(const float* __restrict__ in,
                                                 bf16* __restrict__ out) {
    int i = blockIdx.x * 256 + threadIdx.x;
    const float4* in4 = (const float4*)in;
    float4 a = in4[i * 2];
    float4 b = in4[i * 2 + 1];
    bf16x8 o;
    o[0] = (bf16)a.x; o[1] = (bf16)a.y; o[2] = (bf16)a.z; o[3] = (bf16)a.w;
    o[4] = (bf16)b.x; o[5] = (bf16)b.y; o[6] = (bf16)b.z; o[7] = (bf16)b.w;
    ((bf16x8*)out)[i] = o;
}

// ---------------- stage 0b: transpose fp32 [R][C] -> bf16 [C][R] ----------------
__global__ __launch_bounds__(256) void k_transpose(const float* __restrict__ in,
                                                   bf16* __restrict__ out,
                                                   int R, int C) {
    __shared__ float t[32][33];
    int bx = blockIdx.x * 32;
    int by = blockIdx.y * 32;
    int tx = threadIdx.x, ty = threadIdx.y;
#pragma unroll
    for (int i = 0; i < 32; i += 8)
        t[ty + i][tx] = in[(size_t)(by + ty + i) * C + bx + tx];
    __syncthreads();
#pragma unroll
    for (int i = 0; i < 32; i += 8)
        out[(size_t)(bx + ty + i) * R + by + tx] = (bf16)t[tx][ty + i];
}

// ---------------- stage 0c: sin/cos table [2048][32] {sin,cos} ----------------
__global__ __launch_bounds__(256) void k_sincos(float2* __restrict__ tab) {
    int idx = blockIdx.x * 256 + threadIdx.x;
    int pos = idx >> 5, t = idx & 31;
    float theta = powf(10000.0f, -(float)t * (1.0f / 32.0f));
    float f = (float)pos * theta;
    tab[idx] = make_float2(sinf(f), cosf(f));
}

// ---------------- bf16 GEMM, 128x128 tile, BK=64 ----------------
// global_load_lds staging: LINEAR LDS dest, XOR swizzle pre-applied to the
// global SOURCE chunk (rule #21); ds_reads apply the same XOR.
// Epilogue loops fully unrolled (rule #20).
template <int EPI>
DEV void gemm_body(const bf16* __restrict__ A,
                   const bf16* __restrict__ BT,
                   const float* __restrict__ bias,
                   float* __restrict__ C,
                   bf16* __restrict__ qo,
                   bf16* __restrict__ ko,
                   bf16* __restrict__ vt,
                   const float2* __restrict__ tab,
                   int N, int K) {
    __shared__ uint4 smem4[2048];   // 32KB: A tile 16KB + B tile 16KB
    char* Al = (char*)smem4;
    char* Bl = (char*)smem4 + 16384;
    const int tid = threadIdx.x;
    const int w = tid >> 6, lane = tid & 63, lg = lane >> 4, lr = lane & 15;
    const int m0 = blockIdx.y * 128, n0 = blockIdx.x * 128;
    const int wm = (w >> 1) * 64, wn = (w & 1) * 64;
    const char* Ab = (const char*)A;
    const char* Bb = (const char*)BT;
    const size_t Kb = (size_t)K * 2;

    f32x4 acc[4][4] = {};

    const int rowL = lane >> 3;                    // 0..7 within 8-row group
    const int j16 = ((lane & 7) ^ rowL) * 16;      // pre-swizzled source chunk byte

    for (int kt = 0; kt < K; kt += 64) {
#pragma unroll
        for (int c = 0; c < 4; ++c) {
            const int R0 = (w * 4 + c) * 8;
            const int row = R0 + rowL;
            __builtin_amdgcn_global_load_lds(AS1(Ab + (size_t)(m0 + row) * Kb + kt * 2 + j16),
                                             AS3(Al + R0 * 128), 16, 0, 0);
            __builtin_amdgcn_global_load_lds(AS1(Bb + (size_t)(n0 + row) * Kb + kt * 2 + j16),
                                             AS3(Bl + R0 * 128), 16, 0, 0);
        }
        __syncthreads();
#pragma unroll
        for (int kf = 0; kf < 2; ++kf) {
            bf16x8 af[4], bfr[4];
#pragma unroll
            for (int i = 0; i < 4; ++i) {
                int ra = wm + i * 16 + lr;
                af[i] = *(const bf16x8*)(Al + ra * 128 + ((kf * 64 + lg * 16) ^ ((ra & 7) << 4)));
                int rb = wn + i * 16 + lr;
                bfr[i] = *(const bf16x8*)(Bl + rb * 128 + ((kf * 64 + lg * 16) ^ ((rb & 7) << 4)));
            }
#pragma unroll
            for (int i = 0; i < 4; ++i)
#pragma unroll
                for (int j = 0; j < 4; ++j)
                    acc[i][j] = __builtin_amdgcn_mfma_f32_16x16x32_bf16(af[i], bfr[j], acc[i][j], 0, 0, 0);
        }
        __syncthreads();
    }

    if constexpr (EPI == 0) {
#pragma unroll
        for (int i = 0; i < 4; ++i) {
            int row = m0 + wm + i * 16 + lg * 4;
#pragma unroll
            for (int j = 0; j < 4; ++j) {
                int col = n0 + wn + j * 16 + lr;
                float bv = bias[col];
#pragma unroll
                for (int r = 0; r < 4; ++r)
                    C[(size_t)(row + r) * N + col] = acc[i][j][r] + bv;
            }
        }
    } else {
        const int phase = n0 >> 10;            // 0=q 1=k 2=v
        const int c0 = n0 + wn;
        const int h = (c0 & 1023) >> 6;
        const int b = m0 >> 11;
        const int bh = b * 16 + h;
        const int lbase = (m0 & 2047) + wm;
        float bv[4];
#pragma unroll
        for (int j = 0; j < 4; ++j) bv[j] = bias[c0 + j * 16 + lr];
        float* Lw = (float*)((char*)smem4 + w * 4096);

#pragma unroll   // FULL unroll: compile-time acc indices (rule #20)
        for (int i = 0; i < 4; ++i) {
#pragma unroll
            for (int j = 0; j < 4; ++j)
#pragma unroll
                for (int r = 0; r < 4; ++r)
                    Lw[(lg * 4 + r) * 64 + j * 16 + lr] = acc[i][j][r] + bv[j];
            __syncthreads();
            if (phase < 2) {
                // q gets 1/8 (scores) * log2e (exp2-domain softmax) folded in
                const float scale = (phase == 0) ? 0.125f * LOG2E : 1.0f;
                bf16* dst = (phase == 0 ? qo : ko) + (size_t)bh * Lseq * 64;
#pragma unroll
                for (int j = 0; j < 4; ++j)
#pragma unroll
                    for (int r = 0; r < 4; ++r) {
                        int rl = lg * 4 + r;
                        int d = j * 16 + lr;
                        int l = lbase + i * 16 + rl;
                        float v = Lw[rl * 64 + d];
                        int dp = (d < 32) ? (2 * d + 1) : (2 * d - 64);
                        float p = Lw[rl * 64 + dp];
                        float2 f = tab[l * 32 + (d & 31)];
                        float val = ((d < 32) ? (v - p) * f.x : (v + p) * f.y) * scale;
                        dst[(size_t)l * 64 + d] = (bf16)val;
                    }
            } else {
                int d = lane;
                int lb = lbase + i * 16;
                bf16x8 o1, o2;
#pragma unroll
                for (int rw = 0; rw < 8; ++rw) {
                    o1[rw] = (bf16)Lw[rw * 64 + d];
                    o2[rw] = (bf16)Lw[(rw + 8) * 64 + d];
                }
                bf16* dst = vt + ((size_t)bh * 64 + d) * Lseq + lb;
                *(bf16x8*)dst = o1;
                *(bf16x8*)(dst + 8) = o2;
            }
            __syncthreads();
        }
    }
}

__global__ __launch_bounds__(256) void k_gemm_qkv(const bf16* __restrict__ A,
                                                  const bf16* __restrict__ BT,
                                                  const float* __restrict__ bias,
                                                  bf16* __restrict__ qo,
                                                  bf16* __restrict__ ko,
                                                  bf16* __restrict__ vt,
                                                  const float2* __restrict__ tab) {
    gemm_body<1>(A, BT, bias, nullptr, qo, ko, vt, tab, TN, Dm);
}
__global__ __launch_bounds__(256) void k_gemm_out(const bf16* __restrict__ A,
                                                  const bf16* __restrict__ BT,
                                                  const float* __restrict__ bias,
                                                  float* __restrict__ C) {
    gemm_body<0>(A, BT, bias, C, nullptr, nullptr, nullptr, nullptr, Dm, Dm);
}

// ---------------- stage 3: flash attention (swapped-operand, 32x32x16) ------
// R6: in-block KV-split for occupancy. 8 waves / 512 threads per block:
//   qw = w&3 -> 32-q sub-tile;  s = w>>2 -> KV half (16 tiles each).
// Each half has its own double-buffered 32KB LDS pipeline (64KB total,
// 2 blocks/CU -> 16 waves/CU, 2x round-5's grid-limited 8).
// Waves keep UNnormalized (o, m, l); halves combine via LDS at the end
// (exact log-sum-exp merge), waves 0-3 write the output.
DEV f32x16 mfma32(bf16x8 a, bf16x8 b, f32x16 c) {
    return __builtin_amdgcn_mfma_f32_32x32x16_bf16(a, b, c, 0, 0, 0);
}
DEV unsigned packbf(float lo, float hi) {
    unsigned short a = __builtin_bit_cast(unsigned short, (bf16)lo);
    unsigned short b = __builtin_bit_cast(unsigned short, (bf16)hi);
    return (unsigned)a | ((unsigned)b << 16);
}

DEV void stage_tile(const char* kb, const char* vb, char* Kn, char* Vn,
                    int j0, int qw, int lane) {
#pragma unroll
    for (int c = 0; c < 2; ++c) {
        const int j = qw * 2 + c;              // chunk 0..7 (wave-uniform)
        const int rsw = lane ^ j;              // pre-swizzled source row
        __builtin_amdgcn_global_load_lds(AS1(kb + (size_t)(j0 + rsw) * 128 + j * 16),
                                         AS3(Kn + j * 1024), 16, 0, 0);
        __builtin_amdgcn_global_load_lds(AS1(vb + (size_t)rsw * 4096 + (size_t)j0 * 2 + j * 16),
                                         AS3(Vn + j * 1024), 16, 0, 0);
    }
}

__global__ __launch_bounds__(512, 4) void k_attn(const bf16* __restrict__ Q,
                                                 const bf16* __restrict__ Kt,
                                                 const bf16* __restrict__ Vt,
                                                 bf16* __restrict__ Op) {
    __shared__ uint4 smem4[4096];   // 64KB: 2 halves x (2 bufs x [K 8K | V 8K])
    char* base = (char*)smem4;
    const int tid = threadIdx.x;
    const int w = tid >> 6, lane = tid & 63;
    const int qw = w & 3, s = w >> 2;
    const int hi = lane >> 5, l31 = lane & 31;
    const int bid = blockIdx.x;
    const int bh = bid >> 4, qt = bid & 15;
    const int q0 = qt * 128 + qw * 32;
    const char* qb = (const char*)(Q + (size_t)bh * Lseq * 64);
    const char* kb = (const char*)(Kt + (size_t)bh * Lseq * 64);
    const char* vb = (const char*)(Vt + (size_t)bh * 64 * Lseq);
    char* setb = base + s * 32768;             // this half's pipeline

    // Q frags (B-operand): elem i = Q[q0+l31][kst*16 + hi*8 + i]
    bf16x8 qf[4];
#pragma unroll
    for (int kst = 0; kst < 4; ++kst)
        qf[kst] = *(const bf16x8*)(qb + (size_t)(q0 + l31) * 128 + kst * 32 + hi * 16);

    f32x16 o0 = {}, o1 = {};
    float m = -1e30f, lsum = 0.f;

    // prologue: stage this half's tile 0 into buf 0
    stage_tile(kb, vb, setb, setb + 8192, s * 16 * 64, qw, lane);
    __syncthreads();

    for (int t = 0; t < 16; ++t) {
        const int cur = t & 1;
        const char* Kl = setb + cur * 16384;
        const char* Vl = Kl + 8192;
        char* Kn = setb + (cur ^ 1) * 16384;
        char* Vn = Kn + 8192;

        // async-stage next tile (drains at this iteration's end barrier)
        if (t < 15) stage_tile(kb, vb, Kn, Vn, (s * 16 + t + 1) * 64, qw, lane);

        // S^T = K * Q^T : s0 = j rows 0..31, s1 = 32..63 (col q = l31)
        f32x16 s0 = {}, s1 = {};
        __builtin_amdgcn_s_setprio(1);
#pragma unroll
        for (int kst = 0; kst < 4; ++kst) {
            const int jK = kst * 2 + hi;
            const int x = l31 ^ jK;            // jK<8: flips low 3 bits only
            bf16x8 ka = *(const bf16x8*)(Kl + jK * 1024 + x * 16);
            bf16x8 kc = *(const bf16x8*)(Kl + jK * 1024 + (32 + x) * 16);
            s0 = mfma32(ka, qf[kst], s0);
            s1 = mfma32(kc, qf[kst], s1);
        }
        __builtin_amdgcn_s_setprio(0);

        // lane-local online softmax (exp2 domain) for row q = l31
        float pm = fmaxf(s0[0], s0[1]);
#pragma unroll
        for (int r = 2; r < 16; ++r) pm = fmaxf(pm, s0[r]);
#pragma unroll
        for (int r = 0; r < 16; ++r) pm = fmaxf(pm, s1[r]);
        pm = fmaxf(pm, __shfl_xor(pm, 32));
        if (!__all(pm <= m + 8.0f)) {          // defer-max (T13), log2 units
            float mn = fmaxf(m, pm);
            float sc = exp2_fast(m - mn);
#pragma unroll
            for (int r = 0; r < 16; ++r) { o0[r] *= sc; o1[r] *= sc; }
            lsum *= sc; m = mn;
        }
        float rs = 0.f;
#pragma unroll
        for (int r = 0; r < 16; ++r) { s0[r] = exp2_fast(s0[r] - m); rs += s0[r]; }
#pragma unroll
        for (int r = 0; r < 16; ++r) { s1[r] = exp2_fast(s1[r] - m); rs += s1[r]; }
        rs += __shfl_xor(rs, 32);
        lsum += rs;

        // pack P to bf16 pairs; exchange only the 8 words the partner consumes
        unsigned u[16];
#pragma unroll
        for (int t2 = 0; t2 < 8; ++t2) {
            u[t2]     = packbf(s0[2 * t2], s0[2 * t2 + 1]);
            u[8 + t2] = packbf(s1[2 * t2], s1[2 * t2 + 1]);
        }
        unsigned snd[8], rcv[8];
#pragma unroll
        for (int J = 0; J < 2; ++J)
#pragma unroll
            for (int st = 0; st < 2; ++st) {
                const int t0 = J * 8 + st * 4, q = (J * 2 + st) * 2;
                snd[q + 0] = hi ? u[t0 + 0] : u[t0 + 2];
                snd[q + 1] = hi ? u[t0 + 1] : u[t0 + 3];
            }
#pragma unroll
        for (int t2 = 0; t2 < 8; ++t2) rcv[t2] = __shfl_xor(snd[t2], 32);
        bf16x8 pf[2][2];
#pragma unroll
        for (int J = 0; J < 2; ++J)
#pragma unroll
            for (int st = 0; st < 2; ++st) {
                const int t0 = J * 8 + st * 4, q = (J * 2 + st) * 2;
                union { unsigned wd[4]; bf16x8 v; } f;
                f.wd[0] = hi ? rcv[q + 0] : u[t0 + 0];
                f.wd[1] = hi ? rcv[q + 1] : u[t0 + 1];
                f.wd[2] = hi ? u[t0 + 2] : rcv[q + 0];
                f.wd[3] = hi ? u[t0 + 3] : rcv[q + 1];
                pf[J][st] = f.v;
            }

        // O^T += V^T * P^T : o0 = d rows 0..31, o1 = 32..63 (col q = l31)
        __builtin_amdgcn_s_setprio(1);
#pragma unroll
        for (int J = 0; J < 2; ++J)
#pragma unroll
            for (int st = 0; st < 2; ++st) {
                const int jV = J * 4 + st * 2 + hi;
                const int x = l31 ^ jV;
                bf16x8 v0 = *(const bf16x8*)(Vl + jV * 1024 + x * 16);
                bf16x8 v1 = *(const bf16x8*)(Vl + jV * 1024 + (32 + x) * 16);
                o0 = mfma32(v0, pf[J][st], o0);
                o1 = mfma32(v1, pf[J][st], o1);
            }
        __builtin_amdgcn_s_setprio(0);
        __syncthreads();
    }

    // ---- combine the two KV halves (LDS exchange; K/V buffers now dead) ----
    float* ex = (float*)base;                   // per qw-wave region: 2176 floats
    if (s == 1) {
        float* r = ex + qw * 2176;
#pragma unroll
        for (int t = 0; t < 16; ++t) {
            r[t * 64 + lane] = o0[t];
            r[1024 + t * 64 + lane] = o1[t];
        }
        r[2048 + lane] = m;
        r[2112 + lane] = lsum;
    }
    __syncthreads();
    if (s == 0) {
        float* r = ex + qw * 2176;
        const float mb = r[2048 + lane], lb = r[2112 + lane];
        const float M = fmaxf(m, mb);
        const float wa = exp2_fast(m - M), wb = exp2_fast(mb - M);
        const float inv = 1.0f / (wa * lsum + wb * lb);
        const float fa = wa * inv, fb = wb * inv;
        const int b = bh >> 4, h = bh & 15;
        bf16* dst = Op + (size_t)(b * Lseq + q0 + l31) * Dm + h * 64;
        // epilogue layout: lane owns col q = l31; rows d = (r&3)+8*(r>>2)+4*hi
#pragma unroll
        for (int t = 0; t < 4; ++t) {
            bf16x4 p0, p1;
#pragma unroll
            for (int i = 0; i < 4; ++i) {
                p0[i] = (bf16)(o0[4 * t + i] * fa + r[(4 * t + i) * 64 + lane] * fb);
                p1[i] = (bf16)(o1[4 * t + i] * fa + r[1024 + (4 * t + i) * 64 + lane] * fb);
            }
            *(bf16x4*)(dst + 8 * t + 4 * hi) = p0;
            *(bf16x4*)(dst + 32 + 8 * t + 4 * hi) = p1;
        }
    }
}

// ---------------- launch ----------------
extern "C" void kernel_launch(void* const* d_in, const int* in_sizes, int n_in,
                              void* d_out, int out_size, void* d_ws, size_t ws_size,
                              hipStream_t stream) {
    (void)in_sizes; (void)n_in; (void)out_size; (void)ws_size;
    const float* x    = (const float*)d_in[0];
    const float* Wqkv = (const float*)d_in[1];
    const float* bqkv = (const float*)d_in[2];
    const float* Wout = (const float*)d_in[3];
    const float* bout = (const float*)d_in[4];
    float* out = (float*)d_out;
    char* ws = (char*)d_ws;

    bf16* xbf    = (bf16*)(ws + OFF_XATT);
    bf16* att    = (bf16*)(ws + OFF_XATT);   // aliases xbf (dead after gemm_qkv)
    bf16* wqkvT  = (bf16*)(ws + OFF_WQKVT);
    bf16* woutT  = (bf16*)(ws + OFF_WOUTT);
    float2* tab  = (float2*)(ws + OFF_TAB);
    bf16* qb     = (bf16*)(ws + OFF_Q);
    bf16* kb     = (bf16*)(ws + OFF_K);
    bf16* vt     = (bf16*)(ws + OFF_VT);

    hipLaunchKernelGGL(k_convert, dim3((BL * Dm) / 8 / 256), dim3(256), 0, stream, x, xbf);
    hipLaunchKernelGGL(k_transpose, dim3(TN / 32, Dm / 32), dim3(32, 8), 0, stream, Wqkv, wqkvT, Dm, TN);
    hipLaunchKernelGGL(k_transpose, dim3(Dm / 32, Dm / 32), dim3(32, 8), 0, stream, Wout, woutT, Dm, Dm);
    hipLaunchKernelGGL(k_sincos, dim3(Lseq * 32 / 256), dim3(256), 0, stream, tab);
    hipLaunchKernelGGL(k_gemm_qkv, dim3(TN / 128, BL / 128), dim3(256), 0, stream,
                       xbf, wqkvT, bqkv, qb, kb, vt, tab);
    hipLaunchKernelGGL(k_attn, dim3(32 * 16), dim3(512), 0, stream, qb, kb, vt, att);
    hipLaunchKernelGGL(k_gemm_out, dim3(Dm / 128, BL / 128), dim3(256), 0, stream,
                       att, woutT, bout, out);
}